// Round 1
// baseline (595.231 us; speedup 1.0000x reference)
//
#include <hip/hip_runtime.h>
#include <type_traits>

#define NN 50000
#define NE 600000
#define FEAT 128
#define HID 256

typedef float v2f __attribute__((ext_vector_type(2)));
typedef float v4f __attribute__((ext_vector_type(4)));

// ---------------- CSR build ----------------
__global__ void count_deg_k(const int* __restrict__ dst, int* __restrict__ cnt) {
    int e = blockIdx.x * 256 + threadIdx.x;
    if (e < NE) atomicAdd(&cnt[dst[e]], 1);
}

__global__ __launch_bounds__(1024) void scan_k(const int* __restrict__ cnt,
                                               int* __restrict__ rowptr,
                                               int* __restrict__ cursor) {
    __shared__ int lds[1024];
    const int T = 1024, CH = (NN + T - 1) / T;  // 49
    int t = threadIdx.x;
    int base = t * CH;
    int s = 0;
    for (int i = 0; i < CH; i++) { int idx = base + i; if (idx < NN) s += cnt[idx]; }
    lds[t] = s;
    __syncthreads();
    for (int d = 1; d < T; d <<= 1) {
        int u = (t >= d) ? lds[t - d] : 0;
        __syncthreads();
        lds[t] += u;
        __syncthreads();
    }
    int run = lds[t] - s;  // exclusive prefix
    for (int i = 0; i < CH; i++) {
        int idx = base + i;
        if (idx < NN) { rowptr[idx] = run; cursor[idx] = run; run += cnt[idx]; }
    }
    if (t == T - 1) rowptr[NN] = run;
}

__global__ void fill_k(const int* __restrict__ src, const int* __restrict__ dst,
                       int* __restrict__ cursor, int* __restrict__ col) {
    int e = blockIdx.x * 256 + threadIdx.x;
    if (e < NE) {
        int p = atomicAdd(&cursor[dst[e]], 1);
        col[p] = src[e];
    }
}

// ---------------- aggregation: h_v = (x_v + sum_{u in N(v)} x_u) / (deg+1) ----------------
// one wave per node; lane owns D/64 contiguous floats of the row
template <int D>
__global__ __launch_bounds__(256) void aggregate_k(const float* __restrict__ x,
                                                   const int* __restrict__ rowptr,
                                                   const int* __restrict__ col,
                                                   float* __restrict__ out) {
    constexpr int VPL = D / 64;  // 2 (D=128) or 4 (D=256)
    using VT = std::conditional_t<VPL == 2, v2f, v4f>;
    int wave = threadIdx.x >> 6;
    int lane = threadIdx.x & 63;
    int v = blockIdx.x * 4 + wave;
    if (v >= NN) return;
    int beg = rowptr[v], end = rowptr[v + 1];
    VT acc = *(const VT*)(x + (size_t)v * D + lane * VPL);  // self
    for (int e = beg; e < end; e++) {
        int u = col[e];
        acc += *(const VT*)(x + (size_t)u * D + lane * VPL);
    }
    float inv = 1.0f / (float)(end - beg + 1);
    acc *= inv;
    *(VT*)(out + (size_t)v * D + lane * VPL) = acc;
}

// ---------------- fp32 tiled GEMM: C[M,256] = A[M,K] @ W[K,256] + bias (opt ReLU) ----------------
template <int K, bool RELU>
__global__ __launch_bounds__(256) void gemm_bias_k(const float* __restrict__ A,
                                                   const float* __restrict__ W,
                                                   const float* __restrict__ bias,
                                                   float* __restrict__ C, int M) {
    constexpr int BM = 64, BN = 64, BK = 32;
    __shared__ float As[BK][BM + 4];  // [k][m], pad 4 keeps float4 align + cheap banks
    __shared__ float Bs[BK][BN + 4];  // [k][n]
    int m0 = blockIdx.x * BM;
    int n0 = blockIdx.y * BN;
    int tid = threadIdx.x;
    int tx = tid & 15;         // n micro
    int ty = tid >> 4;         // m micro
    v4f acc[4];
    #pragma unroll
    for (int i = 0; i < 4; i++) acc[i] = (v4f)0.f;

    for (int k0 = 0; k0 < K; k0 += BK) {
        // stage A: 64x32, 8 floats/thread, transposed into As[k][m]
        {
            int r = tid >> 2;            // 0..63
            int c = (tid & 3) * 8;       // 0,8,16,24
            int gm = m0 + r;
            v4f a0 = (v4f)0.f, a1 = (v4f)0.f;
            if (gm < M) {
                a0 = *(const v4f*)(A + (size_t)gm * K + k0 + c);
                a1 = *(const v4f*)(A + (size_t)gm * K + k0 + c + 4);
            }
            As[c + 0][r] = a0[0]; As[c + 1][r] = a0[1];
            As[c + 2][r] = a0[2]; As[c + 3][r] = a0[3];
            As[c + 4][r] = a1[0]; As[c + 5][r] = a1[1];
            As[c + 6][r] = a1[2]; As[c + 7][r] = a1[3];
        }
        // stage B: 32x64, 8 floats/thread, direct layout Bs[k][n]
        {
            int r = tid >> 3;            // 0..31
            int c = (tid & 7) * 8;       // 0..56
            const float* wp = W + (size_t)(k0 + r) * 256 + n0 + c;
            *(v4f*)&Bs[r][c] = *(const v4f*)wp;
            *(v4f*)&Bs[r][c + 4] = *(const v4f*)(wp + 4);
        }
        __syncthreads();
        #pragma unroll
        for (int kk = 0; kk < BK; kk++) {
            v4f a = *(const v4f*)&As[kk][ty * 4];
            v4f b = *(const v4f*)&Bs[kk][tx * 4];
            #pragma unroll
            for (int i = 0; i < 4; i++) {
                float av = a[i];
                acc[i] += b * av;
            }
        }
        __syncthreads();
    }

    v4f b4 = *(const v4f*)&bias[n0 + tx * 4];
    #pragma unroll
    for (int i = 0; i < 4; i++) {
        int gm = m0 + ty * 4 + i;
        if (gm < M) {
            v4f r = acc[i] + b4;
            if (RELU) {
                #pragma unroll
                for (int j = 0; j < 4; j++) r[j] = fmaxf(r[j], 0.f);
            }
            *(v4f*)(C + (size_t)gm * 256 + n0 + tx * 4) = r;
        }
    }
}

// ---------------- final GEMV: out[i] = relu_h3[i,:] @ Wd2 + bd2 ----------------
__global__ __launch_bounds__(256) void gemv_k(const float* __restrict__ h3,
                                              const float* __restrict__ Wd2,
                                              const float* __restrict__ bd2,
                                              float* __restrict__ out) {
    int wave = threadIdx.x >> 6;
    int lane = threadIdx.x & 63;
    int row = blockIdx.x * 4 + wave;
    if (row >= NN) return;
    v4f h = *(const v4f*)(h3 + (size_t)row * 256 + lane * 4);
    v4f w = *(const v4f*)(Wd2 + lane * 4);
    float s = h[0] * w[0] + h[1] * w[1] + h[2] * w[2] + h[3] * w[3];
    #pragma unroll
    for (int m = 32; m >= 1; m >>= 1) s += __shfl_xor(s, m, 64);
    if (lane == 0) out[row] = s + bd2[0];
}

extern "C" void kernel_launch(void* const* d_in, const int* in_sizes, int n_in,
                              void* d_out, int out_size, void* d_ws, size_t ws_size,
                              hipStream_t stream) {
    const float* feats = (const float*)d_in[0];
    const int*   src   = (const int*)d_in[1];
    const int*   dst   = (const int*)d_in[2];
    const float* W1    = (const float*)d_in[3];
    const float* b1    = (const float*)d_in[4];
    const float* W2    = (const float*)d_in[5];
    const float* b2    = (const float*)d_in[6];
    const float* Wd1   = (const float*)d_in[7];
    const float* bd1   = (const float*)d_in[8];
    const float* Wd2   = (const float*)d_in[9];
    const float* bd2   = (const float*)d_in[10];
    float* out = (float*)d_out;

    // workspace layout (~156.6 MB)
    char* base = (char*)d_ws;
    size_t off = 0;
    int* cnt    = (int*)(base + off); off += (size_t)NN * 4;
    int* rowptr = (int*)(base + off); off += (size_t)(NN + 1) * 4;
    int* cursor = (int*)(base + off); off += (size_t)NN * 4;
    int* col    = (int*)(base + off); off += (size_t)NE * 4;
    off = (off + 255) & ~(size_t)255;
    float* bufA = (float*)(base + off); off += (size_t)NN * HID * 4;  // h1
    float* bufB = (float*)(base + off); off += (size_t)NN * HID * 4;  // agg2 -> h3
    float* bufC = (float*)(base + off); off += (size_t)NN * HID * 4;  // agg1 -> h2

    float* agg1 = bufC;   // N x 128 (uses first half of bufC)
    float* h1   = bufA;   // N x 256
    float* agg2 = bufB;   // N x 256
    float* h2   = bufC;   // N x 256 (agg1 dead by then)
    float* h3   = bufB;   // N x 256 (agg2 dead by then)

    hipMemsetAsync(cnt, 0, (size_t)NN * 4, stream);
    count_deg_k<<<(NE + 255) / 256, 256, 0, stream>>>(dst, cnt);
    scan_k<<<1, 1024, 0, stream>>>(cnt, rowptr, cursor);
    fill_k<<<(NE + 255) / 256, 256, 0, stream>>>(src, dst, cursor, col);

    // layer 1: aggregate at d=128 (linearity: agg commutes with matmul), then GEMM+ReLU
    aggregate_k<FEAT><<<(NN + 3) / 4, 256, 0, stream>>>(feats, rowptr, col, agg1);
    gemm_bias_k<FEAT, true><<<dim3((NN + 63) / 64, 4), 256, 0, stream>>>(agg1, W1, b1, h1, NN);

    // layer 2
    aggregate_k<HID><<<(NN + 3) / 4, 256, 0, stream>>>(h1, rowptr, col, agg2);
    gemm_bias_k<HID, false><<<dim3((NN + 63) / 64, 4), 256, 0, stream>>>(agg2, W2, b2, h2, NN);

    // decoder
    gemm_bias_k<HID, true><<<dim3((NN + 63) / 64, 4), 256, 0, stream>>>(h2, Wd1, bd1, h3, NN);
    gemv_k<<<(NN + 3) / 4, 256, 0, stream>>>(h3, Wd2, bd2, out);
}

// Round 2
// 431.822 us; speedup vs baseline: 1.3784x; 1.3784x over previous
//
#include <hip/hip_runtime.h>
#include <type_traits>

#define NN 50000
#define NE 600000
#define FEAT 128
#define HID 256

typedef float v2f __attribute__((ext_vector_type(2)));
typedef float v4f __attribute__((ext_vector_type(4)));
typedef float f32x4 __attribute__((ext_vector_type(4)));
typedef __bf16 bf16x8 __attribute__((ext_vector_type(8)));
using u16 = unsigned short;
using u32 = unsigned int;

__device__ __forceinline__ u16 f2bf(float f) {
    u32 u = __builtin_bit_cast(u32, f);
    u += 0x7fffu + ((u >> 16) & 1u);   // round-to-nearest-even
    return (u16)(u >> 16);
}
__device__ __forceinline__ float bf2f(u16 h) {
    u32 u = ((u32)h) << 16;
    return __builtin_bit_cast(float, u);
}

// ---------------- CSR build ----------------
__global__ void count_deg_k(const int* __restrict__ dst, int* __restrict__ cnt) {
    int e = blockIdx.x * 256 + threadIdx.x;
    if (e < NE) atomicAdd(&cnt[dst[e]], 1);
}

// block-parallel scan: per-block exclusive scan + block sums
__global__ __launch_bounds__(256) void scan1_k(const int* __restrict__ cnt,
                                               int* __restrict__ local,
                                               int* __restrict__ bsum) {
    __shared__ int lds[256];
    int t = threadIdx.x;
    int i = blockIdx.x * 256 + t;
    int v = (i < NN) ? cnt[i] : 0;
    lds[t] = v;
    __syncthreads();
    #pragma unroll
    for (int d = 1; d < 256; d <<= 1) {
        int u = (t >= d) ? lds[t - d] : 0;
        __syncthreads();
        lds[t] += u;
        __syncthreads();
    }
    if (i < NN) local[i] = lds[t] - v;          // exclusive within block
    if (t == 255) bsum[blockIdx.x] = lds[255];  // block total
}

__global__ __launch_bounds__(256) void scan2_k(const int* __restrict__ bsum,
                                               int* __restrict__ boff, int nblk) {
    __shared__ int lds[256];
    int t = threadIdx.x;
    int v = (t < nblk) ? bsum[t] : 0;
    lds[t] = v;
    __syncthreads();
    #pragma unroll
    for (int d = 1; d < 256; d <<= 1) {
        int u = (t >= d) ? lds[t - d] : 0;
        __syncthreads();
        lds[t] += u;
        __syncthreads();
    }
    boff[t] = lds[t] - v;  // exclusive
}

__global__ __launch_bounds__(256) void scan3_k(const int* __restrict__ local,
                                               const int* __restrict__ boff,
                                               int* __restrict__ rowptr,
                                               int* __restrict__ cursor) {
    int i = blockIdx.x * 256 + threadIdx.x;
    if (i < NN) {
        int r = local[i] + boff[blockIdx.x];
        rowptr[i] = r;
        cursor[i] = r;
    }
    if (i == 0) rowptr[NN] = NE;  // every dst is in [0,NN)
}

__global__ void fill_k(const int* __restrict__ src, const int* __restrict__ dst,
                       int* __restrict__ cursor, int* __restrict__ col) {
    int e = blockIdx.x * 256 + threadIdx.x;
    if (e < NE) {
        int p = atomicAdd(&cursor[dst[e]], 1);
        col[p] = src[e];
    }
}

// ------- aggregation, fused bf16x2-split output: h = (x_v + sum_N x_u)/(deg+1) -------
template <int D>
__global__ __launch_bounds__(256) void aggregate_split_k(const float* __restrict__ x,
                                                         const int* __restrict__ rowptr,
                                                         const int* __restrict__ col,
                                                         u16* __restrict__ oh,
                                                         u16* __restrict__ ol) {
    constexpr int VPL = D / 64;  // 2 or 4
    using VT = std::conditional_t<VPL == 2, v2f, v4f>;
    int wave = threadIdx.x >> 6;
    int lane = threadIdx.x & 63;
    int v = blockIdx.x * 4 + wave;
    if (v >= NN) return;
    int beg = rowptr[v], end = rowptr[v + 1];
    VT acc = *(const VT*)(x + (size_t)v * D + lane * VPL);  // self
    for (int e = beg; e < end; e++) {
        int u = col[e];
        acc += *(const VT*)(x + (size_t)u * D + lane * VPL);
    }
    float inv = 1.0f / (float)(end - beg + 1);
    acc *= inv;
    u16 hs[VPL], ls[VPL];
    #pragma unroll
    for (int i = 0; i < VPL; i++) {
        float f = acc[i];
        u16 h = f2bf(f);
        hs[i] = h;
        ls[i] = f2bf(f - bf2f(h));
    }
    size_t base = (size_t)v * D + lane * VPL;
    if constexpr (VPL == 2) {
        *(u32*)(oh + base) = (u32)hs[0] | ((u32)hs[1] << 16);
        *(u32*)(ol + base) = (u32)ls[0] | ((u32)ls[1] << 16);
    } else {
        uint2 H, L;
        H.x = (u32)hs[0] | ((u32)hs[1] << 16);
        H.y = (u32)hs[2] | ((u32)hs[3] << 16);
        L.x = (u32)ls[0] | ((u32)ls[1] << 16);
        L.y = (u32)ls[2] | ((u32)ls[3] << 16);
        *(uint2*)(oh + base) = H;
        *(uint2*)(ol + base) = L;
    }
}

// ------- W prep: transpose + bf16x2 split: W[K][256] -> WT planes [256][K] -------
template <int K>
__global__ void wprep_k(const float* __restrict__ W, u16* __restrict__ WTh,
                        u16* __restrict__ WTl) {
    int idx = blockIdx.x * 256 + threadIdx.x;
    if (idx >= K * 256) return;
    int k = idx >> 8, n = idx & 255;
    float v = W[idx];
    u16 h = f2bf(v);
    WTh[(size_t)n * K + k] = h;
    WTl[(size_t)n * K + k] = f2bf(v - bf2f(h));
}

// ------- MFMA GEMM: C[M,256] = A[M,K] @ W[K,256] + bias  (bf16x2 split, 3 products) -------
// OUTMODE: 0 = fp32 out, 1 = fp32 relu out, 2 = bf16x2-split planes out
template <int K, int OUTMODE>
__global__ __launch_bounds__(512) void mfma_gemm_k(const u16* __restrict__ Ah,
                                                   const u16* __restrict__ Al,
                                                   const u16* __restrict__ BTh,
                                                   const u16* __restrict__ BTl,
                                                   const float* __restrict__ bias,
                                                   float* __restrict__ Cf,
                                                   u16* __restrict__ Ch,
                                                   u16* __restrict__ Cl, int M) {
    int tid = threadIdx.x;
    int wid = tid >> 6, lane = tid & 63;
    int wm = wid >> 2, wn = wid & 3;      // 2 x 4 wave grid
    int m0 = blockIdx.x * 128 + wm * 64;  // wave: 64 rows x 64 cols
    int n0 = wn * 64;
    int r16 = lane & 15;
    int k8 = (lane >> 4) * 8;

    f32x4 acc[4][4];
    #pragma unroll
    for (int a = 0; a < 4; a++)
        #pragma unroll
        for (int b = 0; b < 4; b++) acc[a][b] = (f32x4)0.f;

    int arow[4];
    #pragma unroll
    for (int mf = 0; mf < 4; mf++) {
        int r = m0 + mf * 16 + r16;
        arow[mf] = (r < M) ? r : (M - 1);  // clamp; stores are predicated
    }

    for (int k0 = 0; k0 < K; k0 += 32) {
        bf16x8 ah[4], al[4], bh[4], bl[4];
        #pragma unroll
        for (int mf = 0; mf < 4; mf++) {
            size_t o = (size_t)arow[mf] * K + k0 + k8;
            ah[mf] = *(const bf16x8*)(Ah + o);
            al[mf] = *(const bf16x8*)(Al + o);
        }
        #pragma unroll
        for (int nf = 0; nf < 4; nf++) {
            size_t o = (size_t)(n0 + nf * 16 + r16) * K + k0 + k8;
            bh[nf] = *(const bf16x8*)(BTh + o);
            bl[nf] = *(const bf16x8*)(BTl + o);
        }
        #pragma unroll
        for (int mf = 0; mf < 4; mf++)
            #pragma unroll
            for (int nf = 0; nf < 4; nf++) {
                acc[mf][nf] = __builtin_amdgcn_mfma_f32_16x16x32_bf16(ah[mf], bh[nf], acc[mf][nf], 0, 0, 0);
                acc[mf][nf] = __builtin_amdgcn_mfma_f32_16x16x32_bf16(ah[mf], bl[nf], acc[mf][nf], 0, 0, 0);
                acc[mf][nf] = __builtin_amdgcn_mfma_f32_16x16x32_bf16(al[mf], bh[nf], acc[mf][nf], 0, 0, 0);
            }
    }

    // C/D layout: col = lane&15, row = (lane>>4)*4 + reg
    int rbase = (lane >> 4) * 4;
    #pragma unroll
    for (int mf = 0; mf < 4; mf++) {
        #pragma unroll
        for (int j = 0; j < 4; j++) {
            int gr = m0 + mf * 16 + rbase + j;
            if (gr < M) {
                #pragma unroll
                for (int nf = 0; nf < 4; nf++) {
                    int gc = n0 + nf * 16 + r16;
                    float v = acc[mf][nf][j] + bias[gc];
                    if (OUTMODE == 1) v = fmaxf(v, 0.f);
                    if (OUTMODE == 2) {
                        u16 h = f2bf(v);
                        Ch[(size_t)gr * 256 + gc] = h;
                        Cl[(size_t)gr * 256 + gc] = f2bf(v - bf2f(h));
                    } else {
                        Cf[(size_t)gr * 256 + gc] = v;
                    }
                }
            }
        }
    }
}

// ---------------- final GEMV: out[i] = h3[i,:] @ Wd2 + bd2 ----------------
__global__ __launch_bounds__(256) void gemv_k(const float* __restrict__ h3,
                                              const float* __restrict__ Wd2,
                                              const float* __restrict__ bd2,
                                              float* __restrict__ out) {
    int wave = threadIdx.x >> 6;
    int lane = threadIdx.x & 63;
    int row = blockIdx.x * 4 + wave;
    if (row >= NN) return;
    v4f h = *(const v4f*)(h3 + (size_t)row * 256 + lane * 4);
    v4f w = *(const v4f*)(Wd2 + lane * 4);
    float s = h[0] * w[0] + h[1] * w[1] + h[2] * w[2] + h[3] * w[3];
    #pragma unroll
    for (int m = 32; m >= 1; m >>= 1) s += __shfl_xor(s, m, 64);
    if (lane == 0) out[row] = s + bd2[0];
}

extern "C" void kernel_launch(void* const* d_in, const int* in_sizes, int n_in,
                              void* d_out, int out_size, void* d_ws, size_t ws_size,
                              hipStream_t stream) {
    const float* feats = (const float*)d_in[0];
    const int*   src   = (const int*)d_in[1];
    const int*   dst   = (const int*)d_in[2];
    const float* W1    = (const float*)d_in[3];
    const float* b1    = (const float*)d_in[4];
    const float* W2    = (const float*)d_in[5];
    const float* b2    = (const float*)d_in[6];
    const float* Wd1   = (const float*)d_in[7];
    const float* bd1   = (const float*)d_in[8];
    const float* Wd2   = (const float*)d_in[9];
    const float* bd2   = (const float*)d_in[10];
    float* out = (float*)d_out;

    const int SCAN_BLKS = (NN + 255) / 256;  // 196

    char* base = (char*)d_ws;
    size_t off = 0;
    int* cnt    = (int*)(base + off); off += (size_t)NN * 4;
    int* rowptr = (int*)(base + off); off += (size_t)(NN + 1) * 4;
    int* cursor = (int*)(base + off); off += (size_t)NN * 4;
    int* col    = (int*)(base + off); off += (size_t)NE * 4;
    int* local  = (int*)(base + off); off += (size_t)NN * 4;
    int* bsum   = (int*)(base + off); off += 256 * 4;
    int* boff   = (int*)(base + off); off += 256 * 4;
    u16* WT1h = (u16*)(base + off); off += (size_t)FEAT * 256 * 2;
    u16* WT1l = (u16*)(base + off); off += (size_t)FEAT * 256 * 2;
    u16* WT2h = (u16*)(base + off); off += (size_t)HID * 256 * 2;
    u16* WT2l = (u16*)(base + off); off += (size_t)HID * 256 * 2;
    u16* WTd1h = (u16*)(base + off); off += (size_t)HID * 256 * 2;
    u16* WTd1l = (u16*)(base + off); off += (size_t)HID * 256 * 2;
    off = (off + 255) & ~(size_t)255;
    float* R1 = (float*)(base + off); off += (size_t)NN * HID * 4;   // h1, then h3
    u16* R4h = (u16*)(base + off); off += (size_t)NN * HID * 2;      // A1h / A2h
    u16* R4l = (u16*)(base + off); off += (size_t)NN * HID * 2;      // A1l / A2l
    u16* R5h = (u16*)(base + off); off += (size_t)NN * HID * 2;      // A3h
    u16* R5l = (u16*)(base + off); off += (size_t)NN * HID * 2;      // A3l

    // --- CSR build ---
    hipMemsetAsync(cnt, 0, (size_t)NN * 4, stream);
    count_deg_k<<<(NE + 255) / 256, 256, 0, stream>>>(dst, cnt);
    scan1_k<<<SCAN_BLKS, 256, 0, stream>>>(cnt, local, bsum);
    scan2_k<<<1, 256, 0, stream>>>(bsum, boff, SCAN_BLKS);
    scan3_k<<<SCAN_BLKS, 256, 0, stream>>>(local, boff, rowptr, cursor);
    fill_k<<<(NE + 255) / 256, 256, 0, stream>>>(src, dst, cursor, col);

    // --- weight prep (independent of CSR) ---
    wprep_k<FEAT><<<(FEAT * 256 + 255) / 256, 256, 0, stream>>>(W1, WT1h, WT1l);
    wprep_k<HID><<<(HID * 256 + 255) / 256, 256, 0, stream>>>(W2, WT2h, WT2l);
    wprep_k<HID><<<(HID * 256 + 255) / 256, 256, 0, stream>>>(Wd1, WTd1h, WTd1l);

    const int GEMM_BLKS = (NN + 127) / 128;  // 391

    // layer 1: aggregate at d=128 (agg commutes with matmul), GEMM+ReLU -> h1 (fp32)
    aggregate_split_k<FEAT><<<(NN + 3) / 4, 256, 0, stream>>>(feats, rowptr, col, R4h, R4l);
    mfma_gemm_k<FEAT, 1><<<GEMM_BLKS, 512, 0, stream>>>(R4h, R4l, WT1h, WT1l, b1, R1, nullptr, nullptr, NN);

    // layer 2: aggregate h1, GEMM (no relu) -> split planes for decoder GEMM
    aggregate_split_k<HID><<<(NN + 3) / 4, 256, 0, stream>>>(R1, rowptr, col, R4h, R4l);
    mfma_gemm_k<HID, 2><<<GEMM_BLKS, 512, 0, stream>>>(R4h, R4l, WT2h, WT2l, b2, nullptr, R5h, R5l, NN);

    // decoder: GEMM+ReLU -> h3 (fp32, reuses R1), then GEMV
    mfma_gemm_k<HID, 1><<<GEMM_BLKS, 512, 0, stream>>>(R5h, R5l, WTd1h, WTd1l, bd1, R1, nullptr, nullptr, NN);
    gemv_k<<<(NN + 3) / 4, 256, 0, stream>>>(R1, Wd2, bd2, out);
}

// Round 3
// 360.904 us; speedup vs baseline: 1.6493x; 1.1965x over previous
//
#include <hip/hip_runtime.h>
#include <type_traits>

#define NN 50000
#define NE 600000
#define FEAT 128
#define HID 256

typedef float v2f __attribute__((ext_vector_type(2)));
typedef float v4f __attribute__((ext_vector_type(4)));
typedef float f32x4 __attribute__((ext_vector_type(4)));
typedef __bf16 bf16x8 __attribute__((ext_vector_type(8)));
using u16 = unsigned short;
using u32 = unsigned int;
typedef u16 u16x2 __attribute__((ext_vector_type(2)));
typedef u16 u16x4 __attribute__((ext_vector_type(4)));

__device__ __forceinline__ u16 f2bf(float f) {
    u32 u = __builtin_bit_cast(u32, f);
    u += 0x7fffu + ((u >> 16) & 1u);   // round-to-nearest-even
    return (u16)(u >> 16);
}
__device__ __forceinline__ float bf2f(u16 h) {
    u32 u = ((u32)h) << 16;
    return __builtin_bit_cast(float, u);
}

// ---------------- CSR build ----------------
__global__ void count_deg_k(const int* __restrict__ dst, int* __restrict__ cnt) {
    int e = blockIdx.x * 256 + threadIdx.x;
    if (e < NE) atomicAdd(&cnt[dst[e]], 1);
}

__global__ __launch_bounds__(256) void scan1_k(const int* __restrict__ cnt,
                                               int* __restrict__ local,
                                               int* __restrict__ bsum) {
    __shared__ int lds[256];
    int t = threadIdx.x;
    int i = blockIdx.x * 256 + t;
    int v = (i < NN) ? cnt[i] : 0;
    lds[t] = v;
    __syncthreads();
    #pragma unroll
    for (int d = 1; d < 256; d <<= 1) {
        int u = (t >= d) ? lds[t - d] : 0;
        __syncthreads();
        lds[t] += u;
        __syncthreads();
    }
    if (i < NN) local[i] = lds[t] - v;
    if (t == 255) bsum[blockIdx.x] = lds[255];
}

__global__ __launch_bounds__(256) void scan2_k(const int* __restrict__ bsum,
                                               int* __restrict__ boff, int nblk) {
    __shared__ int lds[256];
    int t = threadIdx.x;
    int v = (t < nblk) ? bsum[t] : 0;
    lds[t] = v;
    __syncthreads();
    #pragma unroll
    for (int d = 1; d < 256; d <<= 1) {
        int u = (t >= d) ? lds[t - d] : 0;
        __syncthreads();
        lds[t] += u;
        __syncthreads();
    }
    boff[t] = lds[t] - v;
}

__global__ __launch_bounds__(256) void scan3_k(const int* __restrict__ local,
                                               const int* __restrict__ boff,
                                               int* __restrict__ rowptr,
                                               int* __restrict__ cursor) {
    int i = blockIdx.x * 256 + threadIdx.x;
    if (i < NN) {
        int r = local[i] + boff[blockIdx.x];
        rowptr[i] = r;
        cursor[i] = r;
    }
    if (i == 0) rowptr[NN] = NE;
}

__global__ void fill_k(const int* __restrict__ src, const int* __restrict__ dst,
                       int* __restrict__ cursor, int* __restrict__ col) {
    int e = blockIdx.x * 256 + threadIdx.x;
    if (e < NE) {
        int p = atomicAdd(&cursor[dst[e]], 1);
        col[p] = src[e];
    }
}

// ---------------- fp32 -> bf16 convert (RNE), 4 elems/thread ----------------
__global__ __launch_bounds__(256) void cvt_bf_k(const float* __restrict__ in,
                                                u16* __restrict__ out, int n4) {
    int i = blockIdx.x * 256 + threadIdx.x;
    if (i >= n4) return;
    v4f v = *(const v4f*)(in + (size_t)i * 4);
    u16x4 o;
    #pragma unroll
    for (int j = 0; j < 4; j++) o[j] = f2bf(v[j]);
    *(u16x4*)(out + (size_t)i * 4) = o;
}

// ------- aggregation from bf16 table, fp32 accumulate, bf16x2-split output -------
template <int D>
__global__ __launch_bounds__(256) void aggregate_bf_split_k(const u16* __restrict__ x,
                                                            const int* __restrict__ rowptr,
                                                            const int* __restrict__ col,
                                                            u16* __restrict__ oh,
                                                            u16* __restrict__ ol) {
    constexpr int VPL = D / 64;  // 2 or 4
    using UT = std::conditional_t<VPL == 2, u16x2, u16x4>;
    int wave = threadIdx.x >> 6;
    int lane = threadIdx.x & 63;
    int v = blockIdx.x * 4 + wave;
    if (v >= NN) return;
    int beg = rowptr[v], end = rowptr[v + 1];
    size_t loff = lane * VPL;
    float acc[VPL];
    {
        UT s = *(const UT*)(x + (size_t)v * D + loff);
        #pragma unroll
        for (int i = 0; i < VPL; i++) acc[i] = bf2f(s[i]);
    }
    int e = beg;
    for (; e + 2 <= end; e += 2) {   // 2 independent gathers in flight
        int u0 = col[e], u1 = col[e + 1];
        UT r0 = *(const UT*)(x + (size_t)u0 * D + loff);
        UT r1 = *(const UT*)(x + (size_t)u1 * D + loff);
        #pragma unroll
        for (int i = 0; i < VPL; i++) acc[i] += bf2f(r0[i]) + bf2f(r1[i]);
    }
    if (e < end) {
        UT r0 = *(const UT*)(x + (size_t)col[e] * D + loff);
        #pragma unroll
        for (int i = 0; i < VPL; i++) acc[i] += bf2f(r0[i]);
    }
    float inv = 1.0f / (float)(end - beg + 1);
    UT H, L;
    #pragma unroll
    for (int i = 0; i < VPL; i++) {
        float f = acc[i] * inv;
        u16 h = f2bf(f);
        H[i] = h;
        L[i] = f2bf(f - bf2f(h));
    }
    size_t base = (size_t)v * D + loff;
    *(UT*)(oh + base) = H;
    *(UT*)(ol + base) = L;
}

// ------- W prep: transpose + bf16x2 split: W[K][256] -> WT planes [256][K] -------
template <int K>
__global__ void wprep_k(const float* __restrict__ W, u16* __restrict__ WTh,
                        u16* __restrict__ WTl) {
    int idx = blockIdx.x * 256 + threadIdx.x;
    if (idx >= K * 256) return;
    int k = idx >> 8, n = idx & 255;
    float v = W[idx];
    u16 h = f2bf(v);
    WTh[(size_t)n * K + k] = h;
    WTl[(size_t)n * K + k] = f2bf(v - bf2f(h));
}

__global__ __launch_bounds__(256) void init_out_k(float* __restrict__ out,
                                                  const float* __restrict__ bd2) {
    int i = blockIdx.x * 256 + threadIdx.x;
    if (i < NN) out[i] = bd2[0];
}

// ------- MFMA GEMM: C[M,256] = A[M,K] @ W[K,256] + bias  (bf16x2 split, 3 products) -------
// OUTMODE: 2 = bf16x2-split planes out, 3 = bf16 single plane + ReLU,
//          4 = fused relu-dot with wd2 -> atomicAdd into out[M]
template <int K, int OUTMODE>
__global__ __launch_bounds__(512) void mfma_gemm_k(const u16* __restrict__ Ah,
                                                   const u16* __restrict__ Al,
                                                   const u16* __restrict__ BTh,
                                                   const u16* __restrict__ BTl,
                                                   const float* __restrict__ bias,
                                                   float* __restrict__ out,
                                                   u16* __restrict__ Ch,
                                                   u16* __restrict__ Cl,
                                                   const float* __restrict__ wd2, int M) {
    int tid = threadIdx.x;
    int wid = tid >> 6, lane = tid & 63;
    int wm = wid >> 2, wn = wid & 3;
    int m0 = blockIdx.x * 128 + wm * 64;
    int n0 = wn * 64;
    int r16 = lane & 15;
    int k8 = (lane >> 4) * 8;

    f32x4 acc[4][4];
    #pragma unroll
    for (int a = 0; a < 4; a++)
        #pragma unroll
        for (int b = 0; b < 4; b++) acc[a][b] = (f32x4)0.f;

    int arow[4];
    #pragma unroll
    for (int mf = 0; mf < 4; mf++) {
        int r = m0 + mf * 16 + r16;
        arow[mf] = (r < M) ? r : (M - 1);
    }

    for (int k0 = 0; k0 < K; k0 += 32) {
        bf16x8 ah[4], al[4], bh[4], bl[4];
        #pragma unroll
        for (int mf = 0; mf < 4; mf++) {
            size_t o = (size_t)arow[mf] * K + k0 + k8;
            ah[mf] = *(const bf16x8*)(Ah + o);
            al[mf] = *(const bf16x8*)(Al + o);
        }
        #pragma unroll
        for (int nf = 0; nf < 4; nf++) {
            size_t o = (size_t)(n0 + nf * 16 + r16) * K + k0 + k8;
            bh[nf] = *(const bf16x8*)(BTh + o);
            bl[nf] = *(const bf16x8*)(BTl + o);
        }
        #pragma unroll
        for (int mf = 0; mf < 4; mf++)
            #pragma unroll
            for (int nf = 0; nf < 4; nf++) {
                acc[mf][nf] = __builtin_amdgcn_mfma_f32_16x16x32_bf16(ah[mf], bh[nf], acc[mf][nf], 0, 0, 0);
                acc[mf][nf] = __builtin_amdgcn_mfma_f32_16x16x32_bf16(ah[mf], bl[nf], acc[mf][nf], 0, 0, 0);
                acc[mf][nf] = __builtin_amdgcn_mfma_f32_16x16x32_bf16(al[mf], bh[nf], acc[mf][nf], 0, 0, 0);
            }
    }

    // C/D layout: col = lane&15, row = (lane>>4)*4 + reg
    int rbase = (lane >> 4) * 4;
    if (OUTMODE == 4) {
        float bias4[4], w4[4];
        #pragma unroll
        for (int nf = 0; nf < 4; nf++) {
            int gc = n0 + nf * 16 + r16;
            bias4[nf] = bias[gc];
            w4[nf] = wd2[gc];
        }
        #pragma unroll
        for (int mf = 0; mf < 4; mf++)
            #pragma unroll
            for (int j = 0; j < 4; j++) {
                int gr = m0 + mf * 16 + rbase + j;
                float s = 0.f;
                #pragma unroll
                for (int nf = 0; nf < 4; nf++)
                    s += fmaxf(acc[mf][nf][j] + bias4[nf], 0.f) * w4[nf];
                s += __shfl_xor(s, 1, 64);
                s += __shfl_xor(s, 2, 64);
                s += __shfl_xor(s, 4, 64);
                s += __shfl_xor(s, 8, 64);
                if (r16 == 0 && gr < M) atomicAdd(out + gr, s);
            }
    } else {
        #pragma unroll
        for (int mf = 0; mf < 4; mf++) {
            #pragma unroll
            for (int j = 0; j < 4; j++) {
                int gr = m0 + mf * 16 + rbase + j;
                if (gr < M) {
                    #pragma unroll
                    for (int nf = 0; nf < 4; nf++) {
                        int gc = n0 + nf * 16 + r16;
                        float v = acc[mf][nf][j] + bias[gc];
                        if (OUTMODE == 3) {
                            Ch[(size_t)gr * 256 + gc] = f2bf(fmaxf(v, 0.f));
                        } else {  // OUTMODE == 2
                            u16 h = f2bf(v);
                            Ch[(size_t)gr * 256 + gc] = h;
                            Cl[(size_t)gr * 256 + gc] = f2bf(v - bf2f(h));
                        }
                    }
                }
            }
        }
    }
}

extern "C" void kernel_launch(void* const* d_in, const int* in_sizes, int n_in,
                              void* d_out, int out_size, void* d_ws, size_t ws_size,
                              hipStream_t stream) {
    const float* feats = (const float*)d_in[0];
    const int*   src   = (const int*)d_in[1];
    const int*   dst   = (const int*)d_in[2];
    const float* W1    = (const float*)d_in[3];
    const float* b1    = (const float*)d_in[4];
    const float* W2    = (const float*)d_in[5];
    const float* b2    = (const float*)d_in[6];
    const float* Wd1   = (const float*)d_in[7];
    const float* bd1   = (const float*)d_in[8];
    const float* Wd2   = (const float*)d_in[9];
    const float* bd2   = (const float*)d_in[10];
    float* out = (float*)d_out;

    const int SCAN_BLKS = (NN + 255) / 256;  // 196

    char* base = (char*)d_ws;
    size_t off = 0;
    int* cnt    = (int*)(base + off); off += (size_t)NN * 4;
    int* rowptr = (int*)(base + off); off += (size_t)(NN + 1) * 4;
    int* cursor = (int*)(base + off); off += (size_t)NN * 4;
    int* col    = (int*)(base + off); off += (size_t)NE * 4;
    int* local  = (int*)(base + off); off += (size_t)NN * 4;
    int* bsum   = (int*)(base + off); off += 256 * 4;
    int* boff   = (int*)(base + off); off += 256 * 4;
    u16* WT1h = (u16*)(base + off); off += (size_t)FEAT * 256 * 2;
    u16* WT1l = (u16*)(base + off); off += (size_t)FEAT * 256 * 2;
    u16* WT2h = (u16*)(base + off); off += (size_t)HID * 256 * 2;
    u16* WT2l = (u16*)(base + off); off += (size_t)HID * 256 * 2;
    u16* WTd1h = (u16*)(base + off); off += (size_t)HID * 256 * 2;
    u16* WTd1l = (u16*)(base + off); off += (size_t)HID * 256 * 2;
    off = (off + 255) & ~(size_t)255;
    u16* featsbf = (u16*)(base + off); off += (size_t)NN * FEAT * 2;  // 12.8 MB
    u16* h1bf    = (u16*)(base + off); off += (size_t)NN * HID * 2;   // 25.6 MB
    u16* R4h = (u16*)(base + off); off += (size_t)NN * HID * 2;       // agg planes
    u16* R4l = (u16*)(base + off); off += (size_t)NN * HID * 2;
    u16* R5h = (u16*)(base + off); off += (size_t)NN * HID * 2;       // gemm2 planes
    u16* R5l = (u16*)(base + off); off += (size_t)NN * HID * 2;

    // --- CSR build ---
    hipMemsetAsync(cnt, 0, (size_t)NN * 4, stream);
    count_deg_k<<<(NE + 255) / 256, 256, 0, stream>>>(dst, cnt);
    scan1_k<<<SCAN_BLKS, 256, 0, stream>>>(cnt, local, bsum);
    scan2_k<<<1, 256, 0, stream>>>(bsum, boff, SCAN_BLKS);
    scan3_k<<<SCAN_BLKS, 256, 0, stream>>>(local, boff, rowptr, cursor);
    fill_k<<<(NE + 255) / 256, 256, 0, stream>>>(src, dst, cursor, col);

    // --- prep (independent of CSR) ---
    wprep_k<FEAT><<<(FEAT * 256 + 255) / 256, 256, 0, stream>>>(W1, WT1h, WT1l);
    wprep_k<HID><<<(HID * 256 + 255) / 256, 256, 0, stream>>>(W2, WT2h, WT2l);
    wprep_k<HID><<<(HID * 256 + 255) / 256, 256, 0, stream>>>(Wd1, WTd1h, WTd1l);
    cvt_bf_k<<<(NN * FEAT / 4 + 255) / 256, 256, 0, stream>>>(feats, featsbf, NN * FEAT / 4);
    init_out_k<<<SCAN_BLKS, 256, 0, stream>>>(out, bd2);

    const int GEMM_BLKS = (NN + 127) / 128;  // 391

    // layer 1: aggregate bf16 feats at d=128, GEMM+ReLU -> h1 (bf16)
    aggregate_bf_split_k<FEAT><<<(NN + 3) / 4, 256, 0, stream>>>(featsbf, rowptr, col, R4h, R4l);
    mfma_gemm_k<FEAT, 3><<<GEMM_BLKS, 512, 0, stream>>>(R4h, R4l, WT1h, WT1l, b1,
                                                        nullptr, h1bf, nullptr, nullptr, NN);

    // layer 2: aggregate bf16 h1, GEMM -> split planes
    aggregate_bf_split_k<HID><<<(NN + 3) / 4, 256, 0, stream>>>(h1bf, rowptr, col, R4h, R4l);
    mfma_gemm_k<HID, 2><<<GEMM_BLKS, 512, 0, stream>>>(R4h, R4l, WT2h, WT2l, b2,
                                                       nullptr, R5h, R5l, nullptr, NN);

    // decoder: GEMM+ReLU fused with final dot (Wd2) -> out
    mfma_gemm_k<HID, 4><<<GEMM_BLKS, 512, 0, stream>>>(R5h, R5l, WTd1h, WTd1l, bd1,
                                                       out, nullptr, nullptr, Wd2, NN);
}

// Round 4
// 333.369 us; speedup vs baseline: 1.7855x; 1.0826x over previous
//
#include <hip/hip_runtime.h>
#include <type_traits>

#define NN 50000
#define NE 600000
#define FEAT 128
#define HID 256

typedef float v4f __attribute__((ext_vector_type(4)));
typedef float f32x4 __attribute__((ext_vector_type(4)));
typedef __bf16 bf16x8 __attribute__((ext_vector_type(8)));
using u16 = unsigned short;
using u32 = unsigned int;
typedef u16 u16x2 __attribute__((ext_vector_type(2)));
typedef u16 u16x4 __attribute__((ext_vector_type(4)));

__device__ __forceinline__ u16 f2bf(float f) {
    u32 u = __builtin_bit_cast(u32, f);
    u += 0x7fffu + ((u >> 16) & 1u);   // RNE
    return (u16)(u >> 16);
}
__device__ __forceinline__ float bf2f(u16 h) {
    u32 u = ((u32)h) << 16;
    return __builtin_bit_cast(float, u);
}

// ---------------- CSR build ----------------
__global__ void count_deg_k(const int* __restrict__ dst, int* __restrict__ cnt) {
    int e = blockIdx.x * 256 + threadIdx.x;
    if (e < NE) atomicAdd(&cnt[dst[e]], 1);
}

__global__ __launch_bounds__(256) void scan1_k(const int* __restrict__ cnt,
                                               int* __restrict__ local,
                                               int* __restrict__ bsum) {
    __shared__ int lds[256];
    int t = threadIdx.x;
    int i = blockIdx.x * 256 + t;
    int v = (i < NN) ? cnt[i] : 0;
    lds[t] = v;
    __syncthreads();
    #pragma unroll
    for (int d = 1; d < 256; d <<= 1) {
        int u = (t >= d) ? lds[t - d] : 0;
        __syncthreads();
        lds[t] += u;
        __syncthreads();
    }
    if (i < NN) local[i] = lds[t] - v;
    if (t == 255) bsum[blockIdx.x] = lds[255];
}

__global__ __launch_bounds__(256) void scan2_k(const int* __restrict__ bsum,
                                               int* __restrict__ boff, int nblk) {
    __shared__ int lds[256];
    int t = threadIdx.x;
    int v = (t < nblk) ? bsum[t] : 0;
    lds[t] = v;
    __syncthreads();
    #pragma unroll
    for (int d = 1; d < 256; d <<= 1) {
        int u = (t >= d) ? lds[t - d] : 0;
        __syncthreads();
        lds[t] += u;
        __syncthreads();
    }
    boff[t] = lds[t] - v;
}

__global__ __launch_bounds__(256) void scan3_k(const int* __restrict__ local,
                                               const int* __restrict__ boff,
                                               int* __restrict__ rowptr,
                                               int* __restrict__ cursor) {
    int i = blockIdx.x * 256 + threadIdx.x;
    if (i < NN) {
        int r = local[i] + boff[blockIdx.x];
        rowptr[i] = r;
        cursor[i] = r;
    }
    if (i == 0) rowptr[NN] = NE;
}

__global__ void fill_k(const int* __restrict__ src, const int* __restrict__ dst,
                       int* __restrict__ cursor, int* __restrict__ col) {
    int e = blockIdx.x * 256 + threadIdx.x;
    if (e < NE) {
        int p = atomicAdd(&cursor[dst[e]], 1);
        col[p] = src[e];
    }
}

// ---------------- fp32 -> bf16 convert (RNE), 4 elems/thread ----------------
__global__ __launch_bounds__(256) void cvt_bf_k(const float* __restrict__ in,
                                                u16* __restrict__ out, int n4) {
    int i = blockIdx.x * 256 + threadIdx.x;
    if (i >= n4) return;
    v4f v = *(const v4f*)(in + (size_t)i * 4);
    u16x4 o;
    #pragma unroll
    for (int j = 0; j < 4; j++) o[j] = f2bf(v[j]);
    *(u16x4*)(out + (size_t)i * 4) = o;
}

// ------- aggregation from bf16 table, fp32 accumulate, bf16 output -------
template <int D>
__global__ __launch_bounds__(256) void aggregate_bf_k(const u16* __restrict__ x,
                                                      const int* __restrict__ rowptr,
                                                      const int* __restrict__ col,
                                                      u16* __restrict__ o) {
    constexpr int VPL = D / 64;  // 2 or 4
    using UT = std::conditional_t<VPL == 2, u16x2, u16x4>;
    int wave = threadIdx.x >> 6;
    int lane = threadIdx.x & 63;
    int v = blockIdx.x * 4 + wave;
    if (v >= NN) return;
    int beg = rowptr[v], end = rowptr[v + 1];
    size_t loff = lane * VPL;
    float acc[VPL];
    {
        UT s = *(const UT*)(x + (size_t)v * D + loff);
        #pragma unroll
        for (int i = 0; i < VPL; i++) acc[i] = bf2f(s[i]);
    }
    int e = beg;
    for (; e + 4 <= end; e += 4) {   // 4 gathers in flight
        int u0 = col[e], u1 = col[e + 1], u2 = col[e + 2], u3 = col[e + 3];
        UT r0 = *(const UT*)(x + (size_t)u0 * D + loff);
        UT r1 = *(const UT*)(x + (size_t)u1 * D + loff);
        UT r2 = *(const UT*)(x + (size_t)u2 * D + loff);
        UT r3 = *(const UT*)(x + (size_t)u3 * D + loff);
        #pragma unroll
        for (int i = 0; i < VPL; i++)
            acc[i] += (bf2f(r0[i]) + bf2f(r1[i])) + (bf2f(r2[i]) + bf2f(r3[i]));
    }
    for (; e < end; e++) {
        UT r0 = *(const UT*)(x + (size_t)col[e] * D + loff);
        #pragma unroll
        for (int i = 0; i < VPL; i++) acc[i] += bf2f(r0[i]);
    }
    float inv = 1.0f / (float)(end - beg + 1);
    UT O;
    #pragma unroll
    for (int i = 0; i < VPL; i++) O[i] = f2bf(acc[i] * inv);
    *(UT*)(o + (size_t)v * D + loff) = O;
}

// ------- W prep: transpose + bf16x2 split: W[K][256] -> WT planes [256][K] -------
template <int K>
__global__ void wprep_k(const float* __restrict__ W, u16* __restrict__ WTh,
                        u16* __restrict__ WTl) {
    int idx = blockIdx.x * 256 + threadIdx.x;
    if (idx >= K * 256) return;
    int k = idx >> 8, n = idx & 255;
    float v = W[idx];
    u16 h = f2bf(v);
    WTh[(size_t)n * K + k] = h;
    WTl[(size_t)n * K + k] = f2bf(v - bf2f(h));
}

__global__ __launch_bounds__(256) void init_out_k(float* __restrict__ out,
                                                  const float* __restrict__ bd2) {
    int i = blockIdx.x * 256 + threadIdx.x;
    if (i < NN) out[i] = bd2[0];
}

// ------- MFMA GEMM: C[M,256] = A[M,K] @ W[K,256] + bias  (W bf16x2 split, 2 products) -------
// Block: 512 thr / 8 waves; tile 64 rows x 256 cols; wave = 64x32 (mf=4, nf=2).
// Register double-buffered k-loop (fully unrolled, static indices).
// OUTMODE: 0 = bf16 out, 1 = bf16 relu out, 2 = fused relu-dot(wd2) -> atomicAdd out
template <int K, int OUTMODE>
__global__ __launch_bounds__(512, 3) void mfma_gemm2_k(const u16* __restrict__ A,
                                                       const u16* __restrict__ BTh,
                                                       const u16* __restrict__ BTl,
                                                       const float* __restrict__ bias,
                                                       u16* __restrict__ C,
                                                       float* __restrict__ out,
                                                       const float* __restrict__ wd2,
                                                       int M) {
    constexpr int KS = K / 32;
    int tid = threadIdx.x;
    int wid = tid >> 6, lane = tid & 63;
    int n0 = wid * 32;
    int m0 = blockIdx.x * 64;
    int r16 = lane & 15;
    int k8 = (lane >> 4) * 8;

    f32x4 acc[4][2];
    #pragma unroll
    for (int a = 0; a < 4; a++)
        #pragma unroll
        for (int b = 0; b < 2; b++) acc[a][b] = (f32x4)0.f;

    int arow[4];
    #pragma unroll
    for (int mf = 0; mf < 4; mf++) {
        int r = m0 + mf * 16 + r16;
        arow[mf] = (r < M) ? r : (M - 1);  // clamp; stores predicated
    }

    bf16x8 af[2][4], bh[2][2], bl[2][2];
    auto LOADK = [&](int buf, int k0) {
        #pragma unroll
        for (int mf = 0; mf < 4; mf++)
            af[buf][mf] = *(const bf16x8*)(A + (size_t)arow[mf] * K + k0 + k8);
        #pragma unroll
        for (int nf = 0; nf < 2; nf++) {
            size_t o = (size_t)(n0 + nf * 16 + r16) * K + k0 + k8;
            bh[buf][nf] = *(const bf16x8*)(BTh + o);
            bl[buf][nf] = *(const bf16x8*)(BTl + o);
        }
    };

    LOADK(0, 0);
    #pragma unroll
    for (int ks = 0; ks < KS; ks++) {
        int cur = ks & 1;
        if (ks + 1 < KS) LOADK(cur ^ 1, (ks + 1) * 32);
        #pragma unroll
        for (int mf = 0; mf < 4; mf++)
            #pragma unroll
            for (int nf = 0; nf < 2; nf++) {
                acc[mf][nf] = __builtin_amdgcn_mfma_f32_16x16x32_bf16(af[cur][mf], bh[cur][nf], acc[mf][nf], 0, 0, 0);
                acc[mf][nf] = __builtin_amdgcn_mfma_f32_16x16x32_bf16(af[cur][mf], bl[cur][nf], acc[mf][nf], 0, 0, 0);
            }
    }

    // C/D layout: col = lane&15, row = (lane>>4)*4 + reg
    int rbase = (lane >> 4) * 4;
    if (OUTMODE == 2) {
        float bias2[2], w2[2];
        #pragma unroll
        for (int nf = 0; nf < 2; nf++) {
            int gc = n0 + nf * 16 + r16;
            bias2[nf] = bias[gc];
            w2[nf] = wd2[gc];
        }
        #pragma unroll
        for (int mf = 0; mf < 4; mf++)
            #pragma unroll
            for (int j = 0; j < 4; j++) {
                int gr = m0 + mf * 16 + rbase + j;
                float s = fmaxf(acc[mf][0][j] + bias2[0], 0.f) * w2[0]
                        + fmaxf(acc[mf][1][j] + bias2[1], 0.f) * w2[1];
                s += __shfl_xor(s, 1, 64);
                s += __shfl_xor(s, 2, 64);
                s += __shfl_xor(s, 4, 64);
                s += __shfl_xor(s, 8, 64);
                if (r16 == 0 && gr < M) atomicAdd(out + gr, s);
            }
    } else {
        #pragma unroll
        for (int mf = 0; mf < 4; mf++)
            #pragma unroll
            for (int j = 0; j < 4; j++) {
                int gr = m0 + mf * 16 + rbase + j;
                if (gr < M) {
                    #pragma unroll
                    for (int nf = 0; nf < 2; nf++) {
                        int gc = n0 + nf * 16 + r16;
                        float v = acc[mf][nf][j] + bias[gc];
                        if (OUTMODE == 1) v = fmaxf(v, 0.f);
                        C[(size_t)gr * 256 + gc] = f2bf(v);
                    }
                }
            }
    }
}

extern "C" void kernel_launch(void* const* d_in, const int* in_sizes, int n_in,
                              void* d_out, int out_size, void* d_ws, size_t ws_size,
                              hipStream_t stream) {
    const float* feats = (const float*)d_in[0];
    const int*   src   = (const int*)d_in[1];
    const int*   dst   = (const int*)d_in[2];
    const float* W1    = (const float*)d_in[3];
    const float* b1    = (const float*)d_in[4];
    const float* W2    = (const float*)d_in[5];
    const float* b2    = (const float*)d_in[6];
    const float* Wd1   = (const float*)d_in[7];
    const float* bd1   = (const float*)d_in[8];
    const float* Wd2   = (const float*)d_in[9];
    const float* bd2   = (const float*)d_in[10];
    float* out = (float*)d_out;

    const int SCAN_BLKS = (NN + 255) / 256;  // 196

    char* base = (char*)d_ws;
    size_t off = 0;
    int* cnt    = (int*)(base + off); off += (size_t)NN * 4;
    int* rowptr = (int*)(base + off); off += (size_t)(NN + 1) * 4;
    int* cursor = (int*)(base + off); off += (size_t)NN * 4;
    int* col    = (int*)(base + off); off += (size_t)NE * 4;
    int* local  = (int*)(base + off); off += (size_t)NN * 4;
    int* bsum   = (int*)(base + off); off += 256 * 4;
    int* boff   = (int*)(base + off); off += 256 * 4;
    u16* WT1h = (u16*)(base + off); off += (size_t)FEAT * 256 * 2;
    u16* WT1l = (u16*)(base + off); off += (size_t)FEAT * 256 * 2;
    u16* WT2h = (u16*)(base + off); off += (size_t)HID * 256 * 2;
    u16* WT2l = (u16*)(base + off); off += (size_t)HID * 256 * 2;
    u16* WTd1h = (u16*)(base + off); off += (size_t)HID * 256 * 2;
    u16* WTd1l = (u16*)(base + off); off += (size_t)HID * 256 * 2;
    off = (off + 255) & ~(size_t)255;
    u16* featsbf = (u16*)(base + off); off += (size_t)NN * FEAT * 2;  // 12.8 MB
    u16* h1bf    = (u16*)(base + off); off += (size_t)NN * HID * 2;   // 25.6 MB
    u16* A1      = (u16*)(base + off); off += (size_t)NN * FEAT * 2;  // agg1 out
    u16* A2      = (u16*)(base + off); off += (size_t)NN * HID * 2;   // agg2 out
    u16* h2bf    = (u16*)(base + off); off += (size_t)NN * HID * 2;   // gemm2 out

    // --- CSR build ---
    hipMemsetAsync(cnt, 0, (size_t)NN * 4, stream);
    count_deg_k<<<(NE + 255) / 256, 256, 0, stream>>>(dst, cnt);
    scan1_k<<<SCAN_BLKS, 256, 0, stream>>>(cnt, local, bsum);
    scan2_k<<<1, 256, 0, stream>>>(bsum, boff, SCAN_BLKS);
    scan3_k<<<SCAN_BLKS, 256, 0, stream>>>(local, boff, rowptr, cursor);
    fill_k<<<(NE + 255) / 256, 256, 0, stream>>>(src, dst, cursor, col);

    // --- prep (independent of CSR) ---
    wprep_k<FEAT><<<(FEAT * 256 + 255) / 256, 256, 0, stream>>>(W1, WT1h, WT1l);
    wprep_k<HID><<<(HID * 256 + 255) / 256, 256, 0, stream>>>(W2, WT2h, WT2l);
    wprep_k<HID><<<(HID * 256 + 255) / 256, 256, 0, stream>>>(Wd1, WTd1h, WTd1l);
    cvt_bf_k<<<(NN * FEAT / 4 + 255) / 256, 256, 0, stream>>>(feats, featsbf, NN * FEAT / 4);
    init_out_k<<<SCAN_BLKS, 256, 0, stream>>>(out, bd2);

    const int GEMM_BLKS = (NN + 63) / 64;  // 782

    // layer 1: aggregate bf16 feats at d=128, GEMM+ReLU -> h1 (bf16)
    aggregate_bf_k<FEAT><<<(NN + 3) / 4, 256, 0, stream>>>(featsbf, rowptr, col, A1);
    mfma_gemm2_k<FEAT, 1><<<GEMM_BLKS, 512, 0, stream>>>(A1, WT1h, WT1l, b1,
                                                         h1bf, nullptr, nullptr, NN);

    // layer 2: aggregate bf16 h1, GEMM -> h2 (bf16)
    aggregate_bf_k<HID><<<(NN + 3) / 4, 256, 0, stream>>>(h1bf, rowptr, col, A2);
    mfma_gemm2_k<HID, 0><<<GEMM_BLKS, 512, 0, stream>>>(A2, WT2h, WT2l, b2,
                                                        h2bf, nullptr, nullptr, NN);

    // decoder: GEMM+ReLU fused with final dot (Wd2) -> out
    mfma_gemm2_k<HID, 2><<<GEMM_BLKS, 512, 0, stream>>>(h2bf, WTd1h, WTd1l, bd1,
                                                        nullptr, out, Wd2, NN);
}

// Round 5
// 245.684 us; speedup vs baseline: 2.4228x; 1.3569x over previous
//
#include <hip/hip_runtime.h>
#include <type_traits>

#define NN 50000
#define NE 600000
#define FEAT 128
#define HID 256

typedef float v4f __attribute__((ext_vector_type(4)));
typedef float f32x4 __attribute__((ext_vector_type(4)));
typedef __bf16 bf16x8 __attribute__((ext_vector_type(8)));
using u16 = unsigned short;
using u32 = unsigned int;
typedef u16 u16x2 __attribute__((ext_vector_type(2)));
typedef u16 u16x4 __attribute__((ext_vector_type(4)));

__device__ __forceinline__ u16 f2bf(float f) {
    u32 u = __builtin_bit_cast(u32, f);
    u += 0x7fffu + ((u >> 16) & 1u);   // RNE
    return (u16)(u >> 16);
}
__device__ __forceinline__ float bf2f(u16 h) {
    u32 u = ((u32)h) << 16;
    return __builtin_bit_cast(float, u);
}

// ---------------- CSR build ----------------
__global__ void count_deg_k(const int* __restrict__ dst, int* __restrict__ cnt) {
    int e = blockIdx.x * 256 + threadIdx.x;
    if (e < NE) atomicAdd(&cnt[dst[e]], 1);
}

__global__ __launch_bounds__(256) void scan1_k(const int* __restrict__ cnt,
                                               int* __restrict__ local,
                                               int* __restrict__ bsum) {
    __shared__ int lds[256];
    int t = threadIdx.x;
    int i = blockIdx.x * 256 + t;
    int v = (i < NN) ? cnt[i] : 0;
    lds[t] = v;
    __syncthreads();
    #pragma unroll
    for (int d = 1; d < 256; d <<= 1) {
        int u = (t >= d) ? lds[t - d] : 0;
        __syncthreads();
        lds[t] += u;
        __syncthreads();
    }
    if (i < NN) local[i] = lds[t] - v;
    if (t == 255) bsum[blockIdx.x] = lds[255];
}

__global__ __launch_bounds__(256) void scan2_k(const int* __restrict__ bsum,
                                               int* __restrict__ boff, int nblk) {
    __shared__ int lds[256];
    int t = threadIdx.x;
    int v = (t < nblk) ? bsum[t] : 0;
    lds[t] = v;
    __syncthreads();
    #pragma unroll
    for (int d = 1; d < 256; d <<= 1) {
        int u = (t >= d) ? lds[t - d] : 0;
        __syncthreads();
        lds[t] += u;
        __syncthreads();
    }
    boff[t] = lds[t] - v;
}

__global__ __launch_bounds__(256) void scan3_k(const int* __restrict__ local,
                                               const int* __restrict__ boff,
                                               int* __restrict__ rowptr,
                                               int* __restrict__ cursor) {
    int i = blockIdx.x * 256 + threadIdx.x;
    if (i < NN) {
        int r = local[i] + boff[blockIdx.x];
        rowptr[i] = r;
        cursor[i] = r;
    }
    if (i == 0) rowptr[NN] = NE;
}

__global__ void fill_k(const int* __restrict__ src, const int* __restrict__ dst,
                       int* __restrict__ cursor, int* __restrict__ col) {
    int e = blockIdx.x * 256 + threadIdx.x;
    if (e < NE) {
        int p = atomicAdd(&cursor[dst[e]], 1);
        col[p] = src[e];
    }
}

// ---------------- fp32 -> bf16 convert (RNE), 4 elems/thread ----------------
__global__ __launch_bounds__(256) void cvt_bf_k(const float* __restrict__ in,
                                                u16* __restrict__ out, int n4) {
    int i = blockIdx.x * 256 + threadIdx.x;
    if (i >= n4) return;
    v4f v = *(const v4f*)(in + (size_t)i * 4);
    u16x4 o;
    #pragma unroll
    for (int j = 0; j < 4; j++) o[j] = f2bf(v[j]);
    *(u16x4*)(out + (size_t)i * 4) = o;
}

// ------- aggregation from bf16 table, fp32 accumulate, bf16 output -------
template <int D>
__global__ __launch_bounds__(256) void aggregate_bf_k(const u16* __restrict__ x,
                                                      const int* __restrict__ rowptr,
                                                      const int* __restrict__ col,
                                                      u16* __restrict__ o) {
    constexpr int VPL = D / 64;  // 2 or 4
    using UT = std::conditional_t<VPL == 2, u16x2, u16x4>;
    int wave = threadIdx.x >> 6;
    int lane = threadIdx.x & 63;
    int v = blockIdx.x * 4 + wave;
    if (v >= NN) return;
    int beg = rowptr[v], end = rowptr[v + 1];
    size_t loff = lane * VPL;
    float acc[VPL];
    {
        UT s = *(const UT*)(x + (size_t)v * D + loff);
        #pragma unroll
        for (int i = 0; i < VPL; i++) acc[i] = bf2f(s[i]);
    }
    int e = beg;
    for (; e + 4 <= end; e += 4) {   // 4 gathers in flight
        int u0 = col[e], u1 = col[e + 1], u2 = col[e + 2], u3 = col[e + 3];
        UT r0 = *(const UT*)(x + (size_t)u0 * D + loff);
        UT r1 = *(const UT*)(x + (size_t)u1 * D + loff);
        UT r2 = *(const UT*)(x + (size_t)u2 * D + loff);
        UT r3 = *(const UT*)(x + (size_t)u3 * D + loff);
        #pragma unroll
        for (int i = 0; i < VPL; i++)
            acc[i] += (bf2f(r0[i]) + bf2f(r1[i])) + (bf2f(r2[i]) + bf2f(r3[i]));
    }
    for (; e < end; e++) {
        UT r0 = *(const UT*)(x + (size_t)col[e] * D + loff);
        #pragma unroll
        for (int i = 0; i < VPL; i++) acc[i] += bf2f(r0[i]);
    }
    float inv = 1.0f / (float)(end - beg + 1);
    UT O;
    #pragma unroll
    for (int i = 0; i < VPL; i++) O[i] = f2bf(acc[i] * inv);
    *(UT*)(o + (size_t)v * D + loff) = O;
}

// ------- W prep: transpose + bf16x2 split: W[K][256] -> WT planes [256][K] -------
template <int K>
__global__ void wprep_k(const float* __restrict__ W, u16* __restrict__ WTh,
                        u16* __restrict__ WTl) {
    int idx = blockIdx.x * 256 + threadIdx.x;
    if (idx >= K * 256) return;
    int k = idx >> 8, n = idx & 255;
    float v = W[idx];
    u16 h = f2bf(v);
    WTh[(size_t)n * K + k] = h;
    WTl[(size_t)n * K + k] = f2bf(v - bf2f(h));
}

__global__ __launch_bounds__(256) void init_out_k(float* __restrict__ out,
                                                  const float* __restrict__ bd2) {
    int i = blockIdx.x * 256 + threadIdx.x;
    if (i < NN) out[i] = bd2[0];
}

// ------- LDS-staged MFMA GEMM: C[M,256] = A[M,K] @ W[K,256] + bias -------
// W pre-split bf16x2 (h,l planes), 2 MFMA products sharing the A fragment.
// Tile: BM=128, BN=128, BK=32. 512 thr = 8 waves (2m x 4n), wave tile 64x32.
// LDS: dbuf x (A 8KB + Bh 8KB + Bl 8KB) = 48KB, slot-swizzled 64B rows.
// OUTMODE: 0 = bf16 out, 1 = bf16 relu out, 2 = fused relu-dot(wd2) -> atomicAdd out
template <int K, int OUTMODE>
__global__ __launch_bounds__(512, 4) void gemm_lds_k(const u16* __restrict__ A,
                                                     const u16* __restrict__ BTh,
                                                     const u16* __restrict__ BTl,
                                                     const float* __restrict__ bias,
                                                     u16* __restrict__ C,
                                                     float* __restrict__ out,
                                                     const float* __restrict__ wd2,
                                                     int M) {
    constexpr int KB = K / 32;
    __shared__ __attribute__((aligned(16))) u16 sA[2][128 * 32];
    __shared__ __attribute__((aligned(16))) u16 sB[2][2][128 * 32];

    int tid = threadIdx.x;
    int wid = tid >> 6, lane = tid & 63;
    int wm = wid >> 2, wn = wid & 3;     // 2 x 4 wave grid
    int m0 = blockIdx.x * 128;
    int nb = blockIdx.y * 128;
    int r16 = lane & 15, sl = lane >> 4;  // sl = logical 16B slot (k/8)

    // --- staging addresses (row = 16B-granular: 4 threads per 64B row) ---
    int st_row = tid >> 2;     // 0..127
    int st_s   = tid & 3;      // logical slot
    int ga_row = m0 + st_row; if (ga_row >= M) ga_row = M - 1;  // clamp
    const u16* gA  = A   + (size_t)ga_row * K + st_s * 8;
    const u16* gBh = BTh + (size_t)(nb + st_row) * K + st_s * 8;
    const u16* gBl = BTl + (size_t)(nb + st_row) * K + st_s * 8;
    // swizzled LDS write offset (u16 units): row*32 + (s ^ ((row>>1)&3))*8
    u32 sw = st_row * 32 + ((st_s ^ ((st_row >> 1) & 3)) * 8);

    // --- fragment read offsets (same swizzle) ---
    int ar0 = wm * 64 + r16, ar1 = ar0 + 16, ar2 = ar0 + 32, ar3 = ar0 + 48;
    u32 ao0 = ar0 * 32 + ((sl ^ ((ar0 >> 1) & 3)) * 8);
    u32 ao1 = ar1 * 32 + ((sl ^ ((ar1 >> 1) & 3)) * 8);
    u32 ao2 = ar2 * 32 + ((sl ^ ((ar2 >> 1) & 3)) * 8);
    u32 ao3 = ar3 * 32 + ((sl ^ ((ar3 >> 1) & 3)) * 8);
    int bc0 = wn * 32 + r16, bc1 = bc0 + 16;
    u32 bo0 = bc0 * 32 + ((sl ^ ((bc0 >> 1) & 3)) * 8);
    u32 bo1 = bc1 * 32 + ((sl ^ ((bc1 >> 1) & 3)) * 8);

    f32x4 acc[4][2];
    #pragma unroll
    for (int a = 0; a < 4; a++)
        #pragma unroll
        for (int b = 0; b < 2; b++) acc[a][b] = (f32x4)0.f;

    // --- prologue: stage kb=0 ---
    uint4 rA  = *(const uint4*)gA;
    uint4 rBh = *(const uint4*)gBh;
    uint4 rBl = *(const uint4*)gBl;
    *(uint4*)(&sA[0][sw])    = rA;
    *(uint4*)(&sB[0][0][sw]) = rBh;
    *(uint4*)(&sB[0][1][sw]) = rBl;
    __syncthreads();

    for (int kb = 0; kb < KB; ++kb) {
        int cur = kb & 1;
        if (kb + 1 < KB) {  // issue next-tile loads early (latency hides under MFMA)
            rA  = *(const uint4*)(gA  + (kb + 1) * 32);
            rBh = *(const uint4*)(gBh + (kb + 1) * 32);
            rBl = *(const uint4*)(gBl + (kb + 1) * 32);
        }
        const u16* pA = sA[cur];
        const u16* pH = sB[cur][0];
        const u16* pL = sB[cur][1];
        bf16x8 a0 = *(const bf16x8*)(pA + ao0);
        bf16x8 a1 = *(const bf16x8*)(pA + ao1);
        bf16x8 a2 = *(const bf16x8*)(pA + ao2);
        bf16x8 a3 = *(const bf16x8*)(pA + ao3);
        bf16x8 h0 = *(const bf16x8*)(pH + bo0);
        bf16x8 h1 = *(const bf16x8*)(pH + bo1);
        bf16x8 l0 = *(const bf16x8*)(pL + bo0);
        bf16x8 l1 = *(const bf16x8*)(pL + bo1);
        acc[0][0] = __builtin_amdgcn_mfma_f32_16x16x32_bf16(a0, h0, acc[0][0], 0, 0, 0);
        acc[0][1] = __builtin_amdgcn_mfma_f32_16x16x32_bf16(a0, h1, acc[0][1], 0, 0, 0);
        acc[1][0] = __builtin_amdgcn_mfma_f32_16x16x32_bf16(a1, h0, acc[1][0], 0, 0, 0);
        acc[1][1] = __builtin_amdgcn_mfma_f32_16x16x32_bf16(a1, h1, acc[1][1], 0, 0, 0);
        acc[2][0] = __builtin_amdgcn_mfma_f32_16x16x32_bf16(a2, h0, acc[2][0], 0, 0, 0);
        acc[2][1] = __builtin_amdgcn_mfma_f32_16x16x32_bf16(a2, h1, acc[2][1], 0, 0, 0);
        acc[3][0] = __builtin_amdgcn_mfma_f32_16x16x32_bf16(a3, h0, acc[3][0], 0, 0, 0);
        acc[3][1] = __builtin_amdgcn_mfma_f32_16x16x32_bf16(a3, h1, acc[3][1], 0, 0, 0);
        acc[0][0] = __builtin_amdgcn_mfma_f32_16x16x32_bf16(a0, l0, acc[0][0], 0, 0, 0);
        acc[0][1] = __builtin_amdgcn_mfma_f32_16x16x32_bf16(a0, l1, acc[0][1], 0, 0, 0);
        acc[1][0] = __builtin_amdgcn_mfma_f32_16x16x32_bf16(a1, l0, acc[1][0], 0, 0, 0);
        acc[1][1] = __builtin_amdgcn_mfma_f32_16x16x32_bf16(a1, l1, acc[1][1], 0, 0, 0);
        acc[2][0] = __builtin_amdgcn_mfma_f32_16x16x32_bf16(a2, l0, acc[2][0], 0, 0, 0);
        acc[2][1] = __builtin_amdgcn_mfma_f32_16x16x32_bf16(a2, l1, acc[2][1], 0, 0, 0);
        acc[3][0] = __builtin_amdgcn_mfma_f32_16x16x32_bf16(a3, l0, acc[3][0], 0, 0, 0);
        acc[3][1] = __builtin_amdgcn_mfma_f32_16x16x32_bf16(a3, l1, acc[3][1], 0, 0, 0);
        if (kb + 1 < KB) {  // write next tile (waits vmcnt here, after MFMAs)
            int nxt = cur ^ 1;
            *(uint4*)(&sA[nxt][sw])    = rA;
            *(uint4*)(&sB[nxt][0][sw]) = rBh;
            *(uint4*)(&sB[nxt][1][sw]) = rBl;
        }
        __syncthreads();
    }

    // --- epilogue. C/D layout: col = lane&15, row = (lane>>4)*4 + reg ---
    int rbase = sl * 4;
    if (OUTMODE == 2) {
        float bias2[2], w2[2];
        #pragma unroll
        for (int nf = 0; nf < 2; nf++) {
            int gc = nb + wn * 32 + nf * 16 + r16;
            bias2[nf] = bias[gc];
            w2[nf] = wd2[gc];
        }
        #pragma unroll
        for (int mf = 0; mf < 4; mf++)
            #pragma unroll
            for (int j = 0; j < 4; j++) {
                int gr = m0 + wm * 64 + mf * 16 + rbase + j;
                float s = fmaxf(acc[mf][0][j] + bias2[0], 0.f) * w2[0]
                        + fmaxf(acc[mf][1][j] + bias2[1], 0.f) * w2[1];
                s += __shfl_xor(s, 1, 64);
                s += __shfl_xor(s, 2, 64);
                s += __shfl_xor(s, 4, 64);
                s += __shfl_xor(s, 8, 64);
                if (r16 == 0 && gr < M) atomicAdd(out + gr, s);
            }
    } else {
        #pragma unroll
        for (int mf = 0; mf < 4; mf++)
            #pragma unroll
            for (int j = 0; j < 4; j++) {
                int gr = m0 + wm * 64 + mf * 16 + rbase + j;
                if (gr < M) {
                    #pragma unroll
                    for (int nf = 0; nf < 2; nf++) {
                        int gc = nb + wn * 32 + nf * 16 + r16;
                        float v = acc[mf][nf][j] + bias[gc];
                        if (OUTMODE == 1) v = fmaxf(v, 0.f);
                        C[(size_t)gr * 256 + gc] = f2bf(v);
                    }
                }
            }
    }
}

extern "C" void kernel_launch(void* const* d_in, const int* in_sizes, int n_in,
                              void* d_out, int out_size, void* d_ws, size_t ws_size,
                              hipStream_t stream) {
    const float* feats = (const float*)d_in[0];
    const int*   src   = (const int*)d_in[1];
    const int*   dst   = (const int*)d_in[2];
    const float* W1    = (const float*)d_in[3];
    const float* b1    = (const float*)d_in[4];
    const float* W2    = (const float*)d_in[5];
    const float* b2    = (const float*)d_in[6];
    const float* Wd1   = (const float*)d_in[7];
    const float* bd1   = (const float*)d_in[8];
    const float* Wd2   = (const float*)d_in[9];
    const float* bd2   = (const float*)d_in[10];
    float* out = (float*)d_out;

    const int SCAN_BLKS = (NN + 255) / 256;  // 196

    char* base = (char*)d_ws;
    size_t off = 0;
    int* cnt    = (int*)(base + off); off += (size_t)NN * 4;
    int* rowptr = (int*)(base + off); off += (size_t)(NN + 1) * 4;
    int* cursor = (int*)(base + off); off += (size_t)NN * 4;
    int* col    = (int*)(base + off); off += (size_t)NE * 4;
    int* local  = (int*)(base + off); off += (size_t)NN * 4;
    int* bsum   = (int*)(base + off); off += 256 * 4;
    int* boff   = (int*)(base + off); off += 256 * 4;
    u16* WT1h = (u16*)(base + off); off += (size_t)FEAT * 256 * 2;
    u16* WT1l = (u16*)(base + off); off += (size_t)FEAT * 256 * 2;
    u16* WT2h = (u16*)(base + off); off += (size_t)HID * 256 * 2;
    u16* WT2l = (u16*)(base + off); off += (size_t)HID * 256 * 2;
    u16* WTd1h = (u16*)(base + off); off += (size_t)HID * 256 * 2;
    u16* WTd1l = (u16*)(base + off); off += (size_t)HID * 256 * 2;
    off = (off + 255) & ~(size_t)255;
    u16* featsbf = (u16*)(base + off); off += (size_t)NN * FEAT * 2;  // 12.8 MB
    u16* h1bf    = (u16*)(base + off); off += (size_t)NN * HID * 2;   // 25.6 MB
    u16* A1      = (u16*)(base + off); off += (size_t)NN * FEAT * 2;  // agg1 out
    u16* A2      = (u16*)(base + off); off += (size_t)NN * HID * 2;   // agg2 out
    u16* h2bf    = (u16*)(base + off); off += (size_t)NN * HID * 2;   // gemm2 out

    // --- CSR build ---
    hipMemsetAsync(cnt, 0, (size_t)NN * 4, stream);
    count_deg_k<<<(NE + 255) / 256, 256, 0, stream>>>(dst, cnt);
    scan1_k<<<SCAN_BLKS, 256, 0, stream>>>(cnt, local, bsum);
    scan2_k<<<1, 256, 0, stream>>>(bsum, boff, SCAN_BLKS);
    scan3_k<<<SCAN_BLKS, 256, 0, stream>>>(local, boff, rowptr, cursor);
    fill_k<<<(NE + 255) / 256, 256, 0, stream>>>(src, dst, cursor, col);

    // --- prep (independent of CSR) ---
    wprep_k<FEAT><<<(FEAT * 256 + 255) / 256, 256, 0, stream>>>(W1, WT1h, WT1l);
    wprep_k<HID><<<(HID * 256 + 255) / 256, 256, 0, stream>>>(W2, WT2h, WT2l);
    wprep_k<HID><<<(HID * 256 + 255) / 256, 256, 0, stream>>>(Wd1, WTd1h, WTd1l);
    cvt_bf_k<<<(NN * FEAT / 4 + 255) / 256, 256, 0, stream>>>(feats, featsbf, NN * FEAT / 4);
    init_out_k<<<SCAN_BLKS, 256, 0, stream>>>(out, bd2);

    const dim3 GEMM_GRID((NN + 127) / 128, 2);  // 391 x 2

    // layer 1: aggregate bf16 feats at d=128, GEMM+ReLU -> h1 (bf16)
    aggregate_bf_k<FEAT><<<(NN + 3) / 4, 256, 0, stream>>>(featsbf, rowptr, col, A1);
    gemm_lds_k<FEAT, 1><<<GEMM_GRID, 512, 0, stream>>>(A1, WT1h, WT1l, b1,
                                                       h1bf, nullptr, nullptr, NN);

    // layer 2: aggregate bf16 h1, GEMM -> h2 (bf16)
    aggregate_bf_k<HID><<<(NN + 3) / 4, 256, 0, stream>>>(h1bf, rowptr, col, A2);
    gemm_lds_k<HID, 0><<<GEMM_GRID, 512, 0, stream>>>(A2, WT2h, WT2l, b2,
                                                      h2bf, nullptr, nullptr, NN);

    // decoder: GEMM+ReLU fused with final dot (Wd2) -> out
    gemm_lds_k<HID, 2><<<GEMM_GRID, 512, 0, stream>>>(h2bf, WTd1h, WTd1l, bd1,
                                                      nullptr, out, Wd2, NN);
}

// Round 6
// 235.839 us; speedup vs baseline: 2.5239x; 1.0417x over previous
//
#include <hip/hip_runtime.h>
#include <type_traits>

#define NN 50000
#define NE 600000
#define FEAT 128
#define HID 256

typedef float v4f __attribute__((ext_vector_type(4)));
typedef float f32x4 __attribute__((ext_vector_type(4)));
typedef __bf16 bf16x8 __attribute__((ext_vector_type(8)));
using u16 = unsigned short;
using u32 = unsigned int;
typedef u16 u16x2 __attribute__((ext_vector_type(2)));
typedef u16 u16x4 __attribute__((ext_vector_type(4)));

__device__ __forceinline__ u16 f2bf(float f) {
    u32 u = __builtin_bit_cast(u32, f);
    u += 0x7fffu + ((u >> 16) & 1u);   // RNE
    return (u16)(u >> 16);
}
__device__ __forceinline__ float bf2f(u16 h) {
    u32 u = ((u32)h) << 16;
    return __builtin_bit_cast(float, u);
}

// ---------------- CSR build ----------------
__global__ void count_deg_k(const int* __restrict__ dst, int* __restrict__ cnt) {
    int e = blockIdx.x * 256 + threadIdx.x;
    if (e < NE) atomicAdd(&cnt[dst[e]], 1);
}

__global__ __launch_bounds__(256) void scan1_k(const int* __restrict__ cnt,
                                               int* __restrict__ local,
                                               int* __restrict__ bsum) {
    __shared__ int lds[256];
    int t = threadIdx.x;
    int i = blockIdx.x * 256 + t;
    int v = (i < NN) ? cnt[i] : 0;
    lds[t] = v;
    __syncthreads();
    #pragma unroll
    for (int d = 1; d < 256; d <<= 1) {
        int u = (t >= d) ? lds[t - d] : 0;
        __syncthreads();
        lds[t] += u;
        __syncthreads();
    }
    if (i < NN) local[i] = lds[t] - v;
    if (t == 255) bsum[blockIdx.x] = lds[255];
}

__global__ __launch_bounds__(256) void scan2_k(const int* __restrict__ bsum,
                                               int* __restrict__ boff, int nblk) {
    __shared__ int lds[256];
    int t = threadIdx.x;
    int v = (t < nblk) ? bsum[t] : 0;
    lds[t] = v;
    __syncthreads();
    #pragma unroll
    for (int d = 1; d < 256; d <<= 1) {
        int u = (t >= d) ? lds[t - d] : 0;
        __syncthreads();
        lds[t] += u;
        __syncthreads();
    }
    boff[t] = lds[t] - v;
}

__global__ __launch_bounds__(256) void scan3_k(const int* __restrict__ local,
                                               const int* __restrict__ boff,
                                               int* __restrict__ rowptr,
                                               int* __restrict__ cursor) {
    int i = blockIdx.x * 256 + threadIdx.x;
    if (i < NN) {
        int r = local[i] + boff[blockIdx.x];
        rowptr[i] = r;
        cursor[i] = r;
    }
    if (i == 0) rowptr[NN] = NE;
}

__global__ void fill_k(const int* __restrict__ src, const int* __restrict__ dst,
                       int* __restrict__ cursor, int* __restrict__ col) {
    int e = blockIdx.x * 256 + threadIdx.x;
    if (e < NE) {
        int p = atomicAdd(&cursor[dst[e]], 1);
        col[p] = src[e];
    }
}

// ---------------- fp32 -> bf16 convert (RNE), 4 elems/thread ----------------
__global__ __launch_bounds__(256) void cvt_bf_k(const float* __restrict__ in,
                                                u16* __restrict__ out, int n4) {
    int i = blockIdx.x * 256 + threadIdx.x;
    if (i >= n4) return;
    v4f v = *(const v4f*)(in + (size_t)i * 4);
    u16x4 o;
    #pragma unroll
    for (int j = 0; j < 4; j++) o[j] = f2bf(v[j]);
    *(u16x4*)(out + (size_t)i * 4) = o;
}

// ------- aggregation from bf16 table, fp32 accumulate, bf16 output (8 gathers in flight) -------
template <int D>
__global__ __launch_bounds__(256) void aggregate_bf_k(const u16* __restrict__ x,
                                                      const int* __restrict__ rowptr,
                                                      const int* __restrict__ col,
                                                      u16* __restrict__ o) {
    constexpr int VPL = D / 64;  // 2 or 4
    using UT = std::conditional_t<VPL == 2, u16x2, u16x4>;
    int wave = threadIdx.x >> 6;
    int lane = threadIdx.x & 63;
    int v = blockIdx.x * 4 + wave;
    if (v >= NN) return;
    int beg = rowptr[v], end = rowptr[v + 1];
    size_t loff = lane * VPL;
    float acc[VPL];
    {
        UT s = *(const UT*)(x + (size_t)v * D + loff);
        #pragma unroll
        for (int i = 0; i < VPL; i++) acc[i] = bf2f(s[i]);
    }
    int e = beg;
    for (; e + 8 <= end; e += 8) {   // 8 gathers in flight
        UT r[8];
        #pragma unroll
        for (int q = 0; q < 8; q++)
            r[q] = *(const UT*)(x + (size_t)col[e + q] * D + loff);
        #pragma unroll
        for (int q = 0; q < 8; q++)
            #pragma unroll
            for (int i = 0; i < VPL; i++) acc[i] += bf2f(r[q][i]);
    }
    for (; e + 2 <= end; e += 2) {
        int u0 = col[e], u1 = col[e + 1];
        UT r0 = *(const UT*)(x + (size_t)u0 * D + loff);
        UT r1 = *(const UT*)(x + (size_t)u1 * D + loff);
        #pragma unroll
        for (int i = 0; i < VPL; i++) acc[i] += bf2f(r0[i]) + bf2f(r1[i]);
    }
    if (e < end) {
        UT r0 = *(const UT*)(x + (size_t)col[e] * D + loff);
        #pragma unroll
        for (int i = 0; i < VPL; i++) acc[i] += bf2f(r0[i]);
    }
    float inv = 1.0f / (float)(end - beg + 1);
    UT O;
    #pragma unroll
    for (int i = 0; i < VPL; i++) O[i] = f2bf(acc[i] * inv);
    *(UT*)(o + (size_t)v * D + loff) = O;
}

// ------- W prep: transpose + bf16x2 split: W[K][256] -> WT planes [256][K] -------
template <int K>
__global__ void wprep_k(const float* __restrict__ W, u16* __restrict__ WTh,
                        u16* __restrict__ WTl) {
    int idx = blockIdx.x * 256 + threadIdx.x;
    if (idx >= K * 256) return;
    int k = idx >> 8, n = idx & 255;
    float v = W[idx];
    u16 h = f2bf(v);
    WTh[(size_t)n * K + k] = h;
    WTl[(size_t)n * K + k] = f2bf(v - bf2f(h));
}

__global__ __launch_bounds__(256) void init_out_k(float* __restrict__ out,
                                                  const float* __restrict__ bd2) {
    int i = blockIdx.x * 256 + threadIdx.x;
    if (i < NN) out[i] = bd2[0];
}

// ------- FUSED gemm1+gemm2: Y2 = relu(A1 @ W1 + b1) @ W2 + b2 (bf16 out) -------
// Exploits agg(Y+1b^T)=agg(Y)+1b^T so layer-2 aggregation runs AFTER this.
// BM=64 rows/block, full N=256. 512 thr = 8 waves, wave tile 64x32 (mf=4,nf=2).
// Phase 1: K=128 GEMM (W1 split) -> relu -> bf16 tile in LDS (sH).
// Phase 2: sH is the A-operand of K=256 GEMM (W2 split) -> Y2 global.
__global__ __launch_bounds__(512, 4) void fused_gemm12_k(const u16* __restrict__ A1,
                                                         const u16* __restrict__ B1h,
                                                         const u16* __restrict__ B1l,
                                                         const float* __restrict__ b1,
                                                         const u16* __restrict__ B2h,
                                                         const u16* __restrict__ B2l,
                                                         const float* __restrict__ b2,
                                                         u16* __restrict__ Y2, int M) {
    __shared__ __attribute__((aligned(16))) u16 sA[64 * 32];        // 4 KB
    __shared__ __attribute__((aligned(16))) u16 sBh[256 * 32];      // 16 KB
    __shared__ __attribute__((aligned(16))) u16 sBl[256 * 32];      // 16 KB
    __shared__ __attribute__((aligned(16))) u16 sH[64 * 264];       // 33 KB (pad +8)

    int tid = threadIdx.x;
    int wid = tid >> 6, lane = tid & 63;
    int m0 = blockIdx.x * 64;
    int r16 = lane & 15, sl = lane >> 4, k8 = sl * 8;

    // fragment offsets (constant per lane)
    u32 ao[4], bo[2];
    #pragma unroll
    for (int mf = 0; mf < 4; mf++) {
        int ar = mf * 16 + r16;
        ao[mf] = ar * 32 + ((sl ^ ((ar >> 1) & 3)) * 8);
    }
    #pragma unroll
    for (int nf = 0; nf < 2; nf++) {
        int bc = wid * 32 + nf * 16 + r16;
        bo[nf] = bc * 32 + ((sl ^ ((bc >> 1) & 3)) * 8);
    }

    f32x4 acc[4][2];
    #pragma unroll
    for (int a = 0; a < 4; a++)
        #pragma unroll
        for (int b = 0; b < 2; b++) acc[a][b] = (f32x4)0.f;

    int st_row = tid >> 2, st_s = tid & 3;

    // ---------------- phase 1: K=128 over A1/W1 ----------------
    #pragma unroll
    for (int kb = 0; kb < 4; kb++) {
        if (tid < 256) {  // A tile: 64 rows x 32 k
            int row = st_row;  // 0..63
            int gr = m0 + row; if (gr >= M) gr = M - 1;
            uint4 v = *(const uint4*)(A1 + (size_t)gr * 128 + kb * 32 + st_s * 8);
            *(uint4*)(&sA[row * 32 + ((st_s ^ ((row >> 1) & 3)) * 8)]) = v;
        }
        #pragma unroll
        for (int i = 0; i < 2; i++) {  // B planes: 256 rows x 32 k
            int row = i * 128 + st_row;
            u32 sw = row * 32 + ((st_s ^ ((row >> 1) & 3)) * 8);
            size_t go = (size_t)row * 128 + kb * 32 + st_s * 8;
            *(uint4*)(&sBh[sw]) = *(const uint4*)(B1h + go);
            *(uint4*)(&sBl[sw]) = *(const uint4*)(B1l + go);
        }
        __syncthreads();
        bf16x8 a0 = *(const bf16x8*)(sA + ao[0]);
        bf16x8 a1 = *(const bf16x8*)(sA + ao[1]);
        bf16x8 a2 = *(const bf16x8*)(sA + ao[2]);
        bf16x8 a3 = *(const bf16x8*)(sA + ao[3]);
        bf16x8 h0 = *(const bf16x8*)(sBh + bo[0]);
        bf16x8 h1 = *(const bf16x8*)(sBh + bo[1]);
        bf16x8 l0 = *(const bf16x8*)(sBl + bo[0]);
        bf16x8 l1 = *(const bf16x8*)(sBl + bo[1]);
        acc[0][0] = __builtin_amdgcn_mfma_f32_16x16x32_bf16(a0, h0, acc[0][0], 0, 0, 0);
        acc[0][1] = __builtin_amdgcn_mfma_f32_16x16x32_bf16(a0, h1, acc[0][1], 0, 0, 0);
        acc[1][0] = __builtin_amdgcn_mfma_f32_16x16x32_bf16(a1, h0, acc[1][0], 0, 0, 0);
        acc[1][1] = __builtin_amdgcn_mfma_f32_16x16x32_bf16(a1, h1, acc[1][1], 0, 0, 0);
        acc[2][0] = __builtin_amdgcn_mfma_f32_16x16x32_bf16(a2, h0, acc[2][0], 0, 0, 0);
        acc[2][1] = __builtin_amdgcn_mfma_f32_16x16x32_bf16(a2, h1, acc[2][1], 0, 0, 0);
        acc[3][0] = __builtin_amdgcn_mfma_f32_16x16x32_bf16(a3, h0, acc[3][0], 0, 0, 0);
        acc[3][1] = __builtin_amdgcn_mfma_f32_16x16x32_bf16(a3, h1, acc[3][1], 0, 0, 0);
        acc[0][0] = __builtin_amdgcn_mfma_f32_16x16x32_bf16(a0, l0, acc[0][0], 0, 0, 0);
        acc[0][1] = __builtin_amdgcn_mfma_f32_16x16x32_bf16(a0, l1, acc[0][1], 0, 0, 0);
        acc[1][0] = __builtin_amdgcn_mfma_f32_16x16x32_bf16(a1, l0, acc[1][0], 0, 0, 0);
        acc[1][1] = __builtin_amdgcn_mfma_f32_16x16x32_bf16(a1, l1, acc[1][1], 0, 0, 0);
        acc[2][0] = __builtin_amdgcn_mfma_f32_16x16x32_bf16(a2, l0, acc[2][0], 0, 0, 0);
        acc[2][1] = __builtin_amdgcn_mfma_f32_16x16x32_bf16(a2, l1, acc[2][1], 0, 0, 0);
        acc[3][0] = __builtin_amdgcn_mfma_f32_16x16x32_bf16(a3, l0, acc[3][0], 0, 0, 0);
        acc[3][1] = __builtin_amdgcn_mfma_f32_16x16x32_bf16(a3, l1, acc[3][1], 0, 0, 0);
        __syncthreads();
    }

    // epilogue 1: +b1, relu, bf16 -> sH[64][264]
    {
        float b1c[2];
        #pragma unroll
        for (int nf = 0; nf < 2; nf++) b1c[nf] = b1[wid * 32 + nf * 16 + r16];
        int rbase = sl * 4;
        #pragma unroll
        for (int mf = 0; mf < 4; mf++)
            #pragma unroll
            for (int j = 0; j < 4; j++) {
                int r = mf * 16 + rbase + j;
                #pragma unroll
                for (int nf = 0; nf < 2; nf++) {
                    int c = wid * 32 + nf * 16 + r16;
                    sH[r * 264 + c] = f2bf(fmaxf(acc[mf][nf][j] + b1c[nf], 0.f));
                }
            }
        #pragma unroll
        for (int a = 0; a < 4; a++)
            #pragma unroll
            for (int b = 0; b < 2; b++) acc[a][b] = (f32x4)0.f;
    }

    // ---------------- phase 2: K=256 over sH/W2 ----------------
    #pragma unroll
    for (int kb = 0; kb < 8; kb++) {
        __syncthreads();  // protects sBh/sBl overwrite AND (first iter) sH completion
        #pragma unroll
        for (int i = 0; i < 2; i++) {
            int row = i * 128 + st_row;
            u32 sw = row * 32 + ((st_s ^ ((row >> 1) & 3)) * 8);
            size_t go = (size_t)row * 256 + kb * 32 + st_s * 8;
            *(uint4*)(&sBh[sw]) = *(const uint4*)(B2h + go);
            *(uint4*)(&sBl[sw]) = *(const uint4*)(B2l + go);
        }
        __syncthreads();
        bf16x8 a0 = *(const bf16x8*)(sH + (0 * 16 + r16) * 264 + kb * 32 + k8);
        bf16x8 a1 = *(const bf16x8*)(sH + (1 * 16 + r16) * 264 + kb * 32 + k8);
        bf16x8 a2 = *(const bf16x8*)(sH + (2 * 16 + r16) * 264 + kb * 32 + k8);
        bf16x8 a3 = *(const bf16x8*)(sH + (3 * 16 + r16) * 264 + kb * 32 + k8);
        bf16x8 h0 = *(const bf16x8*)(sBh + bo[0]);
        bf16x8 h1 = *(const bf16x8*)(sBh + bo[1]);
        bf16x8 l0 = *(const bf16x8*)(sBl + bo[0]);
        bf16x8 l1 = *(const bf16x8*)(sBl + bo[1]);
        acc[0][0] = __builtin_amdgcn_mfma_f32_16x16x32_bf16(a0, h0, acc[0][0], 0, 0, 0);
        acc[0][1] = __builtin_amdgcn_mfma_f32_16x16x32_bf16(a0, h1, acc[0][1], 0, 0, 0);
        acc[1][0] = __builtin_amdgcn_mfma_f32_16x16x32_bf16(a1, h0, acc[1][0], 0, 0, 0);
        acc[1][1] = __builtin_amdgcn_mfma_f32_16x16x32_bf16(a1, h1, acc[1][1], 0, 0, 0);
        acc[2][0] = __builtin_amdgcn_mfma_f32_16x16x32_bf16(a2, h0, acc[2][0], 0, 0, 0);
        acc[2][1] = __builtin_amdgcn_mfma_f32_16x16x32_bf16(a2, h1, acc[2][1], 0, 0, 0);
        acc[3][0] = __builtin_amdgcn_mfma_f32_16x16x32_bf16(a3, h0, acc[3][0], 0, 0, 0);
        acc[3][1] = __builtin_amdgcn_mfma_f32_16x16x32_bf16(a3, h1, acc[3][1], 0, 0, 0);
        acc[0][0] = __builtin_amdgcn_mfma_f32_16x16x32_bf16(a0, l0, acc[0][0], 0, 0, 0);
        acc[0][1] = __builtin_amdgcn_mfma_f32_16x16x32_bf16(a0, l1, acc[0][1], 0, 0, 0);
        acc[1][0] = __builtin_amdgcn_mfma_f32_16x16x32_bf16(a1, l0, acc[1][0], 0, 0, 0);
        acc[1][1] = __builtin_amdgcn_mfma_f32_16x16x32_bf16(a1, l1, acc[1][1], 0, 0, 0);
        acc[2][0] = __builtin_amdgcn_mfma_f32_16x16x32_bf16(a2, l0, acc[2][0], 0, 0, 0);
        acc[2][1] = __builtin_amdgcn_mfma_f32_16x16x32_bf16(a2, l1, acc[2][1], 0, 0, 0);
        acc[3][0] = __builtin_amdgcn_mfma_f32_16x16x32_bf16(a3, l0, acc[3][0], 0, 0, 0);
        acc[3][1] = __builtin_amdgcn_mfma_f32_16x16x32_bf16(a3, l1, acc[3][1], 0, 0, 0);
    }

    // epilogue 2: +b2 -> bf16 -> Y2
    {
        float b2c[2];
        #pragma unroll
        for (int nf = 0; nf < 2; nf++) b2c[nf] = b2[wid * 32 + nf * 16 + r16];
        int rbase = sl * 4;
        #pragma unroll
        for (int mf = 0; mf < 4; mf++)
            #pragma unroll
            for (int j = 0; j < 4; j++) {
                int gr = m0 + mf * 16 + rbase + j;
                if (gr < M) {
                    #pragma unroll
                    for (int nf = 0; nf < 2; nf++) {
                        int gc = wid * 32 + nf * 16 + r16;
                        Y2[(size_t)gr * 256 + gc] = f2bf(acc[mf][nf][j] + b2c[nf]);
                    }
                }
            }
    }
}

// ------- LDS-staged MFMA GEMM (decoder): relu(A@Wd1+bd1) . wd2 -> atomicAdd out -------
// Tile: BM=128, BN=128, BK=32. 512 thr = 8 waves (2m x 4n), wave tile 64x32.
template <int K>
__global__ __launch_bounds__(512, 4) void gemm_dec_k(const u16* __restrict__ A,
                                                     const u16* __restrict__ BTh,
                                                     const u16* __restrict__ BTl,
                                                     const float* __restrict__ bias,
                                                     float* __restrict__ out,
                                                     const float* __restrict__ wd2,
                                                     int M) {
    constexpr int KB = K / 32;
    __shared__ __attribute__((aligned(16))) u16 sA[2][128 * 32];
    __shared__ __attribute__((aligned(16))) u16 sB[2][2][128 * 32];

    int tid = threadIdx.x;
    int wid = tid >> 6, lane = tid & 63;
    int wm = wid >> 2, wn = wid & 3;
    int m0 = blockIdx.x * 128;
    int nb = blockIdx.y * 128;
    int r16 = lane & 15, sl = lane >> 4;

    int st_row = tid >> 2;
    int st_s   = tid & 3;
    int ga_row = m0 + st_row; if (ga_row >= M) ga_row = M - 1;
    const u16* gA  = A   + (size_t)ga_row * K + st_s * 8;
    const u16* gBh = BTh + (size_t)(nb + st_row) * K + st_s * 8;
    const u16* gBl = BTl + (size_t)(nb + st_row) * K + st_s * 8;
    u32 sw = st_row * 32 + ((st_s ^ ((st_row >> 1) & 3)) * 8);

    int ar0 = wm * 64 + r16, ar1 = ar0 + 16, ar2 = ar0 + 32, ar3 = ar0 + 48;
    u32 ao0 = ar0 * 32 + ((sl ^ ((ar0 >> 1) & 3)) * 8);
    u32 ao1 = ar1 * 32 + ((sl ^ ((ar1 >> 1) & 3)) * 8);
    u32 ao2 = ar2 * 32 + ((sl ^ ((ar2 >> 1) & 3)) * 8);
    u32 ao3 = ar3 * 32 + ((sl ^ ((ar3 >> 1) & 3)) * 8);
    int bc0 = wn * 32 + r16, bc1 = bc0 + 16;
    u32 bo0 = bc0 * 32 + ((sl ^ ((bc0 >> 1) & 3)) * 8);
    u32 bo1 = bc1 * 32 + ((sl ^ ((bc1 >> 1) & 3)) * 8);

    f32x4 acc[4][2];
    #pragma unroll
    for (int a = 0; a < 4; a++)
        #pragma unroll
        for (int b = 0; b < 2; b++) acc[a][b] = (f32x4)0.f;

    uint4 rA  = *(const uint4*)gA;
    uint4 rBh = *(const uint4*)gBh;
    uint4 rBl = *(const uint4*)gBl;
    *(uint4*)(&sA[0][sw])    = rA;
    *(uint4*)(&sB[0][0][sw]) = rBh;
    *(uint4*)(&sB[0][1][sw]) = rBl;
    __syncthreads();

    for (int kb = 0; kb < KB; ++kb) {
        int cur = kb & 1;
        if (kb + 1 < KB) {
            rA  = *(const uint4*)(gA  + (kb + 1) * 32);
            rBh = *(const uint4*)(gBh + (kb + 1) * 32);
            rBl = *(const uint4*)(gBl + (kb + 1) * 32);
        }
        const u16* pA = sA[cur];
        const u16* pH = sB[cur][0];
        const u16* pL = sB[cur][1];
        bf16x8 a0 = *(const bf16x8*)(pA + ao0);
        bf16x8 a1 = *(const bf16x8*)(pA + ao1);
        bf16x8 a2 = *(const bf16x8*)(pA + ao2);
        bf16x8 a3 = *(const bf16x8*)(pA + ao3);
        bf16x8 h0 = *(const bf16x8*)(pH + bo0);
        bf16x8 h1 = *(const bf16x8*)(pH + bo1);
        bf16x8 l0 = *(const bf16x8*)(pL + bo0);
        bf16x8 l1 = *(const bf16x8*)(pL + bo1);
        acc[0][0] = __builtin_amdgcn_mfma_f32_16x16x32_bf16(a0, h0, acc[0][0], 0, 0, 0);
        acc[0][1] = __builtin_amdgcn_mfma_f32_16x16x32_bf16(a0, h1, acc[0][1], 0, 0, 0);
        acc[1][0] = __builtin_amdgcn_mfma_f32_16x16x32_bf16(a1, h0, acc[1][0], 0, 0, 0);
        acc[1][1] = __builtin_amdgcn_mfma_f32_16x16x32_bf16(a1, h1, acc[1][1], 0, 0, 0);
        acc[2][0] = __builtin_amdgcn_mfma_f32_16x16x32_bf16(a2, h0, acc[2][0], 0, 0, 0);
        acc[2][1] = __builtin_amdgcn_mfma_f32_16x16x32_bf16(a2, h1, acc[2][1], 0, 0, 0);
        acc[3][0] = __builtin_amdgcn_mfma_f32_16x16x32_bf16(a3, h0, acc[3][0], 0, 0, 0);
        acc[3][1] = __builtin_amdgcn_mfma_f32_16x16x32_bf16(a3, h1, acc[3][1], 0, 0, 0);
        acc[0][0] = __builtin_amdgcn_mfma_f32_16x16x32_bf16(a0, l0, acc[0][0], 0, 0, 0);
        acc[0][1] = __builtin_amdgcn_mfma_f32_16x16x32_bf16(a0, l1, acc[0][1], 0, 0, 0);
        acc[1][0] = __builtin_amdgcn_mfma_f32_16x16x32_bf16(a1, l0, acc[1][0], 0, 0, 0);
        acc[1][1] = __builtin_amdgcn_mfma_f32_16x16x32_bf16(a1, l1, acc[1][1], 0, 0, 0);
        acc[2][0] = __builtin_amdgcn_mfma_f32_16x16x32_bf16(a2, l0, acc[2][0], 0, 0, 0);
        acc[2][1] = __builtin_amdgcn_mfma_f32_16x16x32_bf16(a2, l1, acc[2][1], 0, 0, 0);
        acc[3][0] = __builtin_amdgcn_mfma_f32_16x16x32_bf16(a3, l0, acc[3][0], 0, 0, 0);
        acc[3][1] = __builtin_amdgcn_mfma_f32_16x16x32_bf16(a3, l1, acc[3][1], 0, 0, 0);
        if (kb + 1 < KB) {
            int nxt = cur ^ 1;
            *(uint4*)(&sA[nxt][sw])    = rA;
            *(uint4*)(&sB[nxt][0][sw]) = rBh;
            *(uint4*)(&sB[nxt][1][sw]) = rBl;
        }
        __syncthreads();
    }

    int rbase = sl * 4;
    float bias2[2], w2[2];
    #pragma unroll
    for (int nf = 0; nf < 2; nf++) {
        int gc = nb + wn * 32 + nf * 16 + r16;
        bias2[nf] = bias[gc];
        w2[nf] = wd2[gc];
    }
    #pragma unroll
    for (int mf = 0; mf < 4; mf++)
        #pragma unroll
        for (int j = 0; j < 4; j++) {
            int gr = m0 + wm * 64 + mf * 16 + rbase + j;
            float s = fmaxf(acc[mf][0][j] + bias2[0], 0.f) * w2[0]
                    + fmaxf(acc[mf][1][j] + bias2[1], 0.f) * w2[1];
            s += __shfl_xor(s, 1, 64);
            s += __shfl_xor(s, 2, 64);
            s += __shfl_xor(s, 4, 64);
            s += __shfl_xor(s, 8, 64);
            if (r16 == 0 && gr < M) atomicAdd(out + gr, s);
        }
}

extern "C" void kernel_launch(void* const* d_in, const int* in_sizes, int n_in,
                              void* d_out, int out_size, void* d_ws, size_t ws_size,
                              hipStream_t stream) {
    const float* feats = (const float*)d_in[0];
    const int*   src   = (const int*)d_in[1];
    const int*   dst   = (const int*)d_in[2];
    const float* W1    = (const float*)d_in[3];
    const float* b1    = (const float*)d_in[4];
    const float* W2    = (const float*)d_in[5];
    const float* b2    = (const float*)d_in[6];
    const float* Wd1   = (const float*)d_in[7];
    const float* bd1   = (const float*)d_in[8];
    const float* Wd2   = (const float*)d_in[9];
    const float* bd2   = (const float*)d_in[10];
    float* out = (float*)d_out;

    const int SCAN_BLKS = (NN + 255) / 256;  // 196

    char* base = (char*)d_ws;
    size_t off = 0;
    int* cnt    = (int*)(base + off); off += (size_t)NN * 4;
    int* rowptr = (int*)(base + off); off += (size_t)(NN + 1) * 4;
    int* cursor = (int*)(base + off); off += (size_t)NN * 4;
    int* col    = (int*)(base + off); off += (size_t)NE * 4;
    int* local  = (int*)(base + off); off += (size_t)NN * 4;
    int* bsum   = (int*)(base + off); off += 256 * 4;
    int* boff   = (int*)(base + off); off += 256 * 4;
    u16* WT1h = (u16*)(base + off); off += (size_t)FEAT * 256 * 2;
    u16* WT1l = (u16*)(base + off); off += (size_t)FEAT * 256 * 2;
    u16* WT2h = (u16*)(base + off); off += (size_t)HID * 256 * 2;
    u16* WT2l = (u16*)(base + off); off += (size_t)HID * 256 * 2;
    u16* WTd1h = (u16*)(base + off); off += (size_t)HID * 256 * 2;
    u16* WTd1l = (u16*)(base + off); off += (size_t)HID * 256 * 2;
    off = (off + 255) & ~(size_t)255;
    u16* featsbf = (u16*)(base + off); off += (size_t)NN * FEAT * 2;  // 12.8 MB
    u16* A1      = (u16*)(base + off); off += (size_t)NN * FEAT * 2;  // agg1 out
    u16* Y2bf    = (u16*)(base + off); off += (size_t)NN * HID * 2;   // fused gemm12 out
    u16* h2bf    = (u16*)(base + off); off += (size_t)NN * HID * 2;   // agg2 out

    // --- CSR build ---
    hipMemsetAsync(cnt, 0, (size_t)NN * 4, stream);
    count_deg_k<<<(NE + 255) / 256, 256, 0, stream>>>(dst, cnt);
    scan1_k<<<SCAN_BLKS, 256, 0, stream>>>(cnt, local, bsum);
    scan2_k<<<1, 256, 0, stream>>>(bsum, boff, SCAN_BLKS);
    scan3_k<<<SCAN_BLKS, 256, 0, stream>>>(local, boff, rowptr, cursor);
    fill_k<<<(NE + 255) / 256, 256, 0, stream>>>(src, dst, cursor, col);

    // --- prep (independent of CSR) ---
    wprep_k<FEAT><<<(FEAT * 256 + 255) / 256, 256, 0, stream>>>(W1, WT1h, WT1l);
    wprep_k<HID><<<(HID * 256 + 255) / 256, 256, 0, stream>>>(W2, WT2h, WT2l);
    wprep_k<HID><<<(HID * 256 + 255) / 256, 256, 0, stream>>>(Wd1, WTd1h, WTd1l);
    cvt_bf_k<<<(NN * FEAT / 4 + 255) / 256, 256, 0, stream>>>(feats, featsbf, NN * FEAT / 4);
    init_out_k<<<SCAN_BLKS, 256, 0, stream>>>(out, bd2);

    // layer 1 aggregate (d=128): feats_bf -> A1
    aggregate_bf_k<FEAT><<<(NN + 3) / 4, 256, 0, stream>>>(featsbf, rowptr, col, A1);

    // fused layer1 GEMM + relu + layer2 GEMM: A1 -> Y2 (pre-aggregation, bias included)
    fused_gemm12_k<<<(NN + 63) / 64, 512, 0, stream>>>(A1, WT1h, WT1l, b1,
                                                       WT2h, WT2l, b2, Y2bf, NN);

    // layer 2 aggregate (d=256): Y2 -> h2 (agg commutes with matmul+bias)
    aggregate_bf_k<HID><<<(NN + 3) / 4, 256, 0, stream>>>(Y2bf, rowptr, col, h2bf);

    // decoder: relu(h2@Wd1+bd1) . Wd2 + bd2 -> out
    gemm_dec_k<HID><<<dim3((NN + 127) / 128, 2), 512, 0, stream>>>(h2bf, WTd1h, WTd1l, bd1,
                                                                   out, Wd2, NN);
}

// Round 7
// 209.565 us; speedup vs baseline: 2.8403x; 1.1254x over previous
//
#include <hip/hip_runtime.h>
#include <type_traits>

#define NN 50000
#define NE 600000
#define FEAT 128
#define HID 256

typedef float v4f __attribute__((ext_vector_type(4)));
typedef float f32x4 __attribute__((ext_vector_type(4)));
typedef __bf16 bf16x8 __attribute__((ext_vector_type(8)));
using u16 = unsigned short;
using u32 = unsigned int;
typedef u16 u16x4 __attribute__((ext_vector_type(4)));
typedef u16 u16x8 __attribute__((ext_vector_type(8)));

__device__ __forceinline__ u16 f2bf(float f) {
    u32 u = __builtin_bit_cast(u32, f);
    u += 0x7fffu + ((u >> 16) & 1u);   // RNE
    return (u16)(u >> 16);
}
__device__ __forceinline__ float bf2f(u16 h) {
    u32 u = ((u32)h) << 16;
    return __builtin_bit_cast(float, u);
}

// ---------------- CSR build ----------------
__global__ void count_deg_k(const int* __restrict__ dst, int* __restrict__ cnt) {
    int e = blockIdx.x * 256 + threadIdx.x;
    if (e < NE) atomicAdd(&cnt[dst[e]], 1);
}

__global__ __launch_bounds__(256) void scan1_k(const int* __restrict__ cnt,
                                               int* __restrict__ local,
                                               int* __restrict__ bsum) {
    __shared__ int lds[256];
    int t = threadIdx.x;
    int i = blockIdx.x * 256 + t;
    int v = (i < NN) ? cnt[i] : 0;
    lds[t] = v;
    __syncthreads();
    #pragma unroll
    for (int d = 1; d < 256; d <<= 1) {
        int u = (t >= d) ? lds[t - d] : 0;
        __syncthreads();
        lds[t] += u;
        __syncthreads();
    }
    if (i < NN) local[i] = lds[t] - v;
    if (t == 255) bsum[blockIdx.x] = lds[255];
}

// merged scan2+scan3: every block redundantly scans the 196 block sums in LDS
__global__ __launch_bounds__(256) void scan_apply_k(const int* __restrict__ local,
                                                    const int* __restrict__ bsum,
                                                    int* __restrict__ rowptr,
                                                    int* __restrict__ cursor, int nblk) {
    __shared__ int lds[256];
    int t = threadIdx.x;
    int v = (t < nblk) ? bsum[t] : 0;
    lds[t] = v;
    __syncthreads();
    #pragma unroll
    for (int d = 1; d < 256; d <<= 1) {
        int u = (t >= d) ? lds[t - d] : 0;
        __syncthreads();
        lds[t] += u;
        __syncthreads();
    }
    int boff = lds[blockIdx.x] - bsum[blockIdx.x];  // exclusive prefix for this block
    int i = blockIdx.x * 256 + t;
    if (i < NN) {
        int r = local[i] + boff;
        rowptr[i] = r;
        cursor[i] = r;
    }
    if (blockIdx.x == 0 && t == 0) rowptr[NN] = NE;
}

__global__ void fill_k(const int* __restrict__ src, const int* __restrict__ dst,
                       int* __restrict__ cursor, int* __restrict__ col) {
    int e = blockIdx.x * 256 + threadIdx.x;
    if (e < NE) {
        int p = atomicAdd(&cursor[dst[e]], 1);
        col[p] = src[e];
    }
}

// ---------------- combined prep: cvt feats, transpose+cvt W1/W2/Wd1, init out ----------------
#define NB_CVT 6250           // NN*FEAT/4/256
#define NB_W1  128            // 128*256/256
#define NB_W2  256
#define NB_WD1 256
#define NB_OUT 196
__global__ __launch_bounds__(256) void prep_k(const float* __restrict__ feats,
                                              const float* __restrict__ W1,
                                              const float* __restrict__ W2,
                                              const float* __restrict__ Wd1,
                                              const float* __restrict__ bd2,
                                              u16* __restrict__ featsbf,
                                              u16* __restrict__ WT1,
                                              u16* __restrict__ WT2,
                                              u16* __restrict__ WTd1,
                                              float* __restrict__ out) {
    int b = blockIdx.x, t = threadIdx.x;
    if (b < NB_CVT) {
        int i = b * 256 + t;  // exactly NN*FEAT/4 items
        v4f v = *(const v4f*)(feats + (size_t)i * 4);
        u16x4 o;
        #pragma unroll
        for (int j = 0; j < 4; j++) o[j] = f2bf(v[j]);
        *(u16x4*)(featsbf + (size_t)i * 4) = o;
    } else if (b < NB_CVT + NB_W1) {
        int idx = (b - NB_CVT) * 256 + t;
        int k = idx >> 8, n = idx & 255;
        WT1[(size_t)n * 128 + k] = f2bf(W1[idx]);
    } else if (b < NB_CVT + NB_W1 + NB_W2) {
        int idx = (b - NB_CVT - NB_W1) * 256 + t;
        int k = idx >> 8, n = idx & 255;
        WT2[(size_t)n * 256 + k] = f2bf(W2[idx]);
    } else if (b < NB_CVT + NB_W1 + NB_W2 + NB_WD1) {
        int idx = (b - NB_CVT - NB_W1 - NB_W2) * 256 + t;
        int k = idx >> 8, n = idx & 255;
        WTd1[(size_t)n * 256 + k] = f2bf(Wd1[idx]);
    } else {
        int i = (b - NB_CVT - NB_W1 - NB_W2 - NB_WD1) * 256 + t;
        if (i < NN) out[i] = bd2[0];
    }
}

// ------- aggregation: grouped 16B/lane gathers, G edges in parallel per step -------
// self row folded in as virtual edge #deg. fp32 accumulate, bf16 output.
template <int D>
__global__ __launch_bounds__(256) void aggregate_bf_k(const u16* __restrict__ x,
                                                      const int* __restrict__ rowptr,
                                                      const int* __restrict__ col,
                                                      u16* __restrict__ o) {
    constexpr int LPG = (D == 256) ? 32 : 16;  // lanes per group (group covers one row)
    constexpr int G = 64 / LPG;                // edges per step: 2 (D=256), 4 (D=128)
    int wave = threadIdx.x >> 6;
    int lane = threadIdx.x & 63;
    int v = blockIdx.x * 4 + wave;
    if (v >= NN) return;
    int g  = lane / LPG;
    int li = lane & (LPG - 1);
    size_t coff = (size_t)li * 8;              // 8 bf16 cols = 16B per lane
    int beg = rowptr[v];
    int deg = rowptr[v + 1] - beg;
    int cnt = deg + 1;                         // + self
    float acc[8];
    #pragma unroll
    for (int i = 0; i < 8; i++) acc[i] = 0.f;
    int base = 0;
    #pragma unroll 4
    for (; base + G <= cnt; base += G) {
        int idx = base + g;
        int row = (idx < deg) ? col[beg + idx] : v;
        u16x8 r = *(const u16x8*)(x + (size_t)row * D + coff);
        #pragma unroll
        for (int i = 0; i < 8; i++) acc[i] += bf2f(r[i]);
    }
    if (base + g < cnt) {
        int idx = base + g;
        int row = (idx < deg) ? col[beg + idx] : v;
        u16x8 r = *(const u16x8*)(x + (size_t)row * D + coff);
        #pragma unroll
        for (int i = 0; i < 8; i++) acc[i] += bf2f(r[i]);
    }
    #pragma unroll
    for (int i = 0; i < 8; i++) {
        acc[i] += __shfl_xor(acc[i], 32, 64);
        if (G == 4) acc[i] += __shfl_xor(acc[i], 16, 64);
    }
    if (lane < LPG) {
        float inv = 1.0f / (float)cnt;
        u16x8 O;
        #pragma unroll
        for (int i = 0; i < 8; i++) O[i] = f2bf(acc[i] * inv);
        *(u16x8*)(o + (size_t)v * D + coff) = O;
    }
}

#define MFMA_BF16 __builtin_amdgcn_mfma_f32_16x16x32_bf16

// ------- FUSED gemm1+gemm2: Y2 = relu(A1 @ W1 + b1) @ W2 + b2 (bf16 out) -------
// Single-plane bf16 W, reg-dbuf staging both phases.
// BM=64 rows/block, 512 thr = 8 waves over N=256 (wave 64x32, mf=4 nf=2).
__global__ __launch_bounds__(512, 4) void fused_gemm12_k(const u16* __restrict__ A1,
                                                         const u16* __restrict__ B1,
                                                         const float* __restrict__ b1,
                                                         const u16* __restrict__ B2,
                                                         const float* __restrict__ b2,
                                                         u16* __restrict__ Y2, int M) {
    __shared__ __attribute__((aligned(16))) u16 sA[2][64 * 32];    // 8 KB
    __shared__ __attribute__((aligned(16))) u16 sB[2][256 * 32];   // 32 KB
    __shared__ __attribute__((aligned(16))) u16 sH[64 * 264];      // 33 KB (pad +8)

    int tid = threadIdx.x;
    int wid = tid >> 6, lane = tid & 63;
    int m0 = blockIdx.x * 64;
    int r16 = lane & 15, sl = lane >> 4, k8 = sl * 8;

    u32 ao[4], bo[2];
    #pragma unroll
    for (int mf = 0; mf < 4; mf++) {
        int ar = mf * 16 + r16;
        ao[mf] = ar * 32 + ((sl ^ ((ar >> 1) & 3)) * 8);
    }
    #pragma unroll
    for (int nf = 0; nf < 2; nf++) {
        int bc = wid * 32 + nf * 16 + r16;
        bo[nf] = bc * 32 + ((sl ^ ((bc >> 1) & 3)) * 8);
    }

    f32x4 acc[4][2];
    #pragma unroll
    for (int a = 0; a < 4; a++)
        #pragma unroll
        for (int b = 0; b < 2; b++) acc[a][b] = (f32x4)0.f;

    // staging maps
    int aRow = tid >> 2, aS = tid & 3;                       // A: tid<256
    u32 aSw = aRow * 32 + ((aS ^ ((aRow >> 1) & 3)) * 8);
    int gAr = m0 + aRow; if (gAr >= M) gAr = M - 1;
    const u16* gA = A1 + (size_t)gAr * 128 + aS * 8;
    int bRow[2], bS[2]; u32 bSw[2];
    #pragma unroll
    for (int j = 0; j < 2; j++) {
        int idx = tid + j * 512;
        bRow[j] = idx >> 2; bS[j] = idx & 3;
        bSw[j] = bRow[j] * 32 + ((bS[j] ^ ((bRow[j] >> 1) & 3)) * 8);
    }

    uint4 rA, rB0, rB1;

    // ---------------- phase 1: K=128 over A1/W1 ----------------
    if (tid < 256) rA = *(const uint4*)gA;
    rB0 = *(const uint4*)(B1 + (size_t)bRow[0] * 128 + bS[0] * 8);
    rB1 = *(const uint4*)(B1 + (size_t)bRow[1] * 128 + bS[1] * 8);
    if (tid < 256) *(uint4*)(&sA[0][aSw]) = rA;
    *(uint4*)(&sB[0][bSw[0]]) = rB0;
    *(uint4*)(&sB[0][bSw[1]]) = rB1;
    __syncthreads();

    #pragma unroll
    for (int kb = 0; kb < 4; kb++) {
        int cur = kb & 1;
        if (kb < 3) {
            if (tid < 256) rA = *(const uint4*)(gA + (kb + 1) * 32);
            rB0 = *(const uint4*)(B1 + (size_t)bRow[0] * 128 + (kb + 1) * 32 + bS[0] * 8);
            rB1 = *(const uint4*)(B1 + (size_t)bRow[1] * 128 + (kb + 1) * 32 + bS[1] * 8);
        }
        bf16x8 a0 = *(const bf16x8*)(&sA[cur][ao[0]]);
        bf16x8 a1 = *(const bf16x8*)(&sA[cur][ao[1]]);
        bf16x8 a2 = *(const bf16x8*)(&sA[cur][ao[2]]);
        bf16x8 a3 = *(const bf16x8*)(&sA[cur][ao[3]]);
        bf16x8 h0 = *(const bf16x8*)(&sB[cur][bo[0]]);
        bf16x8 h1 = *(const bf16x8*)(&sB[cur][bo[1]]);
        acc[0][0] = MFMA_BF16(a0, h0, acc[0][0], 0, 0, 0);
        acc[0][1] = MFMA_BF16(a0, h1, acc[0][1], 0, 0, 0);
        acc[1][0] = MFMA_BF16(a1, h0, acc[1][0], 0, 0, 0);
        acc[1][1] = MFMA_BF16(a1, h1, acc[1][1], 0, 0, 0);
        acc[2][0] = MFMA_BF16(a2, h0, acc[2][0], 0, 0, 0);
        acc[2][1] = MFMA_BF16(a2, h1, acc[2][1], 0, 0, 0);
        acc[3][0] = MFMA_BF16(a3, h0, acc[3][0], 0, 0, 0);
        acc[3][1] = MFMA_BF16(a3, h1, acc[3][1], 0, 0, 0);
        if (kb < 3) {
            int nxt = cur ^ 1;
            if (tid < 256) *(uint4*)(&sA[nxt][aSw]) = rA;
            *(uint4*)(&sB[nxt][bSw[0]]) = rB0;
            *(uint4*)(&sB[nxt][bSw[1]]) = rB1;
        }
        __syncthreads();
    }

    // issue phase-2 kb0 B loads early (hide under epilogue-1)
    rB0 = *(const uint4*)(B2 + (size_t)bRow[0] * 256 + bS[0] * 8);
    rB1 = *(const uint4*)(B2 + (size_t)bRow[1] * 256 + bS[1] * 8);

    // epilogue 1: +b1, relu, bf16 -> sH
    {
        float b1c[2];
        #pragma unroll
        for (int nf = 0; nf < 2; nf++) b1c[nf] = b1[wid * 32 + nf * 16 + r16];
        int rbase = sl * 4;
        #pragma unroll
        for (int mf = 0; mf < 4; mf++)
            #pragma unroll
            for (int j = 0; j < 4; j++) {
                int r = mf * 16 + rbase + j;
                #pragma unroll
                for (int nf = 0; nf < 2; nf++) {
                    int c = wid * 32 + nf * 16 + r16;
                    sH[r * 264 + c] = f2bf(fmaxf(acc[mf][nf][j] + b1c[nf], 0.f));
                }
            }
        #pragma unroll
        for (int a = 0; a < 4; a++)
            #pragma unroll
            for (int b = 0; b < 2; b++) acc[a][b] = (f32x4)0.f;
    }
    *(uint4*)(&sB[0][bSw[0]]) = rB0;   // phase-1 sB reads all done (last barrier)
    *(uint4*)(&sB[0][bSw[1]]) = rB1;
    __syncthreads();                   // sH + sB[0] ready

    // ---------------- phase 2: K=256 over sH/W2 (dbuf) ----------------
    #pragma unroll
    for (int kb = 0; kb < 8; kb++) {
        int cur = kb & 1;
        if (kb < 7) {
            rB0 = *(const uint4*)(B2 + (size_t)bRow[0] * 256 + (kb + 1) * 32 + bS[0] * 8);
            rB1 = *(const uint4*)(B2 + (size_t)bRow[1] * 256 + (kb + 1) * 32 + bS[1] * 8);
        }
        bf16x8 a0 = *(const bf16x8*)(sH + (0 * 16 + r16) * 264 + kb * 32 + k8);
        bf16x8 a1 = *(const bf16x8*)(sH + (1 * 16 + r16) * 264 + kb * 32 + k8);
        bf16x8 a2 = *(const bf16x8*)(sH + (2 * 16 + r16) * 264 + kb * 32 + k8);
        bf16x8 a3 = *(const bf16x8*)(sH + (3 * 16 + r16) * 264 + kb * 32 + k8);
        bf16x8 h0 = *(const bf16x8*)(&sB[cur][bo[0]]);
        bf16x8 h1 = *(const bf16x8*)(&sB[cur][bo[1]]);
        acc[0][0] = MFMA_BF16(a0, h0, acc[0][0], 0, 0, 0);
        acc[0][1] = MFMA_BF16(a0, h1, acc[0][1], 0, 0, 0);
        acc[1][0] = MFMA_BF16(a1, h0, acc[1][0], 0, 0, 0);
        acc[1][1] = MFMA_BF16(a1, h1, acc[1][1], 0, 0, 0);
        acc[2][0] = MFMA_BF16(a2, h0, acc[2][0], 0, 0, 0);
        acc[2][1] = MFMA_BF16(a2, h1, acc[2][1], 0, 0, 0);
        acc[3][0] = MFMA_BF16(a3, h0, acc[3][0], 0, 0, 0);
        acc[3][1] = MFMA_BF16(a3, h1, acc[3][1], 0, 0, 0);
        if (kb < 7) {
            int nxt = cur ^ 1;
            *(uint4*)(&sB[nxt][bSw[0]]) = rB0;
            *(uint4*)(&sB[nxt][bSw[1]]) = rB1;
        }
        __syncthreads();
    }

    // epilogue 2: +b2 -> bf16 -> Y2
    {
        float b2c[2];
        #pragma unroll
        for (int nf = 0; nf < 2; nf++) b2c[nf] = b2[wid * 32 + nf * 16 + r16];
        int rbase = sl * 4;
        #pragma unroll
        for (int mf = 0; mf < 4; mf++)
            #pragma unroll
            for (int j = 0; j < 4; j++) {
                int gr = m0 + mf * 16 + rbase + j;
                if (gr < M) {
                    #pragma unroll
                    for (int nf = 0; nf < 2; nf++) {
                        int gc = wid * 32 + nf * 16 + r16;
                        Y2[(size_t)gr * 256 + gc] = f2bf(acc[mf][nf][j] + b2c[nf]);
                    }
                }
            }
    }
}

// ------- decoder GEMM: relu(A@Wd1+bd1) . wd2 -> atomicAdd out (single-plane W) -------
// Tile BM=128, BN=128, BK=32; 512 thr = 8 waves (2m x 4n), wave 64x32.
template <int K>
__global__ __launch_bounds__(512, 4) void gemm_dec_k(const u16* __restrict__ A,
                                                     const u16* __restrict__ BT,
                                                     const float* __restrict__ bias,
                                                     float* __restrict__ out,
                                                     const float* __restrict__ wd2,
                                                     int M) {
    constexpr int KB = K / 32;
    __shared__ __attribute__((aligned(16))) u16 sA[2][128 * 32];
    __shared__ __attribute__((aligned(16))) u16 sB[2][128 * 32];

    int tid = threadIdx.x;
    int wid = tid >> 6, lane = tid & 63;
    int wm = wid >> 2, wn = wid & 3;
    int m0 = blockIdx.x * 128;
    int nb = blockIdx.y * 128;
    int r16 = lane & 15, sl = lane >> 4;

    int st_row = tid >> 2;
    int st_s   = tid & 3;
    int ga_row = m0 + st_row; if (ga_row >= M) ga_row = M - 1;
    const u16* gA = A  + (size_t)ga_row * K + st_s * 8;
    const u16* gB = BT + (size_t)(nb + st_row) * K + st_s * 8;
    u32 sw = st_row * 32 + ((st_s ^ ((st_row >> 1) & 3)) * 8);

    u32 ao[4], bo[2];
    #pragma unroll
    for (int mf = 0; mf < 4; mf++) {
        int ar = wm * 64 + mf * 16 + r16;
        ao[mf] = ar * 32 + ((sl ^ ((ar >> 1) & 3)) * 8);
    }
    #pragma unroll
    for (int nf = 0; nf < 2; nf++) {
        int bc = wn * 32 + nf * 16 + r16;
        bo[nf] = bc * 32 + ((sl ^ ((bc >> 1) & 3)) * 8);
    }

    f32x4 acc[4][2];
    #pragma unroll
    for (int a = 0; a < 4; a++)
        #pragma unroll
        for (int b = 0; b < 2; b++) acc[a][b] = (f32x4)0.f;

    uint4 rA = *(const uint4*)gA;
    uint4 rB = *(const uint4*)gB;
    *(uint4*)(&sA[0][sw]) = rA;
    *(uint4*)(&sB[0][sw]) = rB;
    __syncthreads();

    #pragma unroll
    for (int kb = 0; kb < KB; ++kb) {
        int cur = kb & 1;
        if (kb + 1 < KB) {
            rA = *(const uint4*)(gA + (kb + 1) * 32);
            rB = *(const uint4*)(gB + (kb + 1) * 32);
        }
        bf16x8 a0 = *(const bf16x8*)(&sA[cur][ao[0]]);
        bf16x8 a1 = *(const bf16x8*)(&sA[cur][ao[1]]);
        bf16x8 a2 = *(const bf16x8*)(&sA[cur][ao[2]]);
        bf16x8 a3 = *(const bf16x8*)(&sA[cur][ao[3]]);
        bf16x8 h0 = *(const bf16x8*)(&sB[cur][bo[0]]);
        bf16x8 h1 = *(const bf16x8*)(&sB[cur][bo[1]]);
        acc[0][0] = MFMA_BF16(a0, h0, acc[0][0], 0, 0, 0);
        acc[0][1] = MFMA_BF16(a0, h1, acc[0][1], 0, 0, 0);
        acc[1][0] = MFMA_BF16(a1, h0, acc[1][0], 0, 0, 0);
        acc[1][1] = MFMA_BF16(a1, h1, acc[1][1], 0, 0, 0);
        acc[2][0] = MFMA_BF16(a2, h0, acc[2][0], 0, 0, 0);
        acc[2][1] = MFMA_BF16(a2, h1, acc[2][1], 0, 0, 0);
        acc[3][0] = MFMA_BF16(a3, h0, acc[3][0], 0, 0, 0);
        acc[3][1] = MFMA_BF16(a3, h1, acc[3][1], 0, 0, 0);
        if (kb + 1 < KB) {
            int nxt = cur ^ 1;
            *(uint4*)(&sA[nxt][sw]) = rA;
            *(uint4*)(&sB[nxt][sw]) = rB;
        }
        __syncthreads();
    }

    int rbase = sl * 4;
    float bias2[2], w2[2];
    #pragma unroll
    for (int nf = 0; nf < 2; nf++) {
        int gc = nb + wn * 32 + nf * 16 + r16;
        bias2[nf] = bias[gc];
        w2[nf] = wd2[gc];
    }
    #pragma unroll
    for (int mf = 0; mf < 4; mf++)
        #pragma unroll
        for (int j = 0; j < 4; j++) {
            int gr = m0 + wm * 64 + mf * 16 + rbase + j;
            float s = fmaxf(acc[mf][0][j] + bias2[0], 0.f) * w2[0]
                    + fmaxf(acc[mf][1][j] + bias2[1], 0.f) * w2[1];
            s += __shfl_xor(s, 1, 64);
            s += __shfl_xor(s, 2, 64);
            s += __shfl_xor(s, 4, 64);
            s += __shfl_xor(s, 8, 64);
            if (r16 == 0 && gr < M) atomicAdd(out + gr, s);
        }
}

extern "C" void kernel_launch(void* const* d_in, const int* in_sizes, int n_in,
                              void* d_out, int out_size, void* d_ws, size_t ws_size,
                              hipStream_t stream) {
    const float* feats = (const float*)d_in[0];
    const int*   src   = (const int*)d_in[1];
    const int*   dst   = (const int*)d_in[2];
    const float* W1    = (const float*)d_in[3];
    const float* b1    = (const float*)d_in[4];
    const float* W2    = (const float*)d_in[5];
    const float* b2    = (const float*)d_in[6];
    const float* Wd1   = (const float*)d_in[7];
    const float* bd1   = (const float*)d_in[8];
    const float* Wd2   = (const float*)d_in[9];
    const float* bd2   = (const float*)d_in[10];
    float* out = (float*)d_out;

    const int SCAN_BLKS = (NN + 255) / 256;  // 196

    char* base = (char*)d_ws;
    size_t off = 0;
    int* cnt    = (int*)(base + off); off += (size_t)NN * 4;
    int* rowptr = (int*)(base + off); off += (size_t)(NN + 1) * 4;
    int* cursor = (int*)(base + off); off += (size_t)NN * 4;
    int* col    = (int*)(base + off); off += (size_t)NE * 4;
    int* local  = (int*)(base + off); off += (size_t)NN * 4;
    int* bsum   = (int*)(base + off); off += 256 * 4;
    u16* WT1  = (u16*)(base + off); off += (size_t)FEAT * 256 * 2;
    u16* WT2  = (u16*)(base + off); off += (size_t)HID * 256 * 2;
    u16* WTd1 = (u16*)(base + off); off += (size_t)HID * 256 * 2;
    off = (off + 255) & ~(size_t)255;
    u16* featsbf = (u16*)(base + off); off += (size_t)NN * FEAT * 2;  // 12.8 MB
    u16* A1      = (u16*)(base + off); off += (size_t)NN * FEAT * 2;  // agg1 out
    u16* Y2bf    = (u16*)(base + off); off += (size_t)NN * HID * 2;   // fused out
    u16* h2bf    = (u16*)(base + off); off += (size_t)NN * HID * 2;   // agg2 out

    // --- CSR build ---
    hipMemsetAsync(cnt, 0, (size_t)NN * 4, stream);
    count_deg_k<<<(NE + 255) / 256, 256, 0, stream>>>(dst, cnt);
    scan1_k<<<SCAN_BLKS, 256, 0, stream>>>(cnt, local, bsum);
    scan_apply_k<<<SCAN_BLKS, 256, 0, stream>>>(local, bsum, rowptr, cursor, SCAN_BLKS);
    fill_k<<<(NE + 255) / 256, 256, 0, stream>>>(src, dst, cursor, col);

    // --- combined prep (independent of CSR) ---
    prep_k<<<NB_CVT + NB_W1 + NB_W2 + NB_WD1 + NB_OUT, 256, 0, stream>>>(
        feats, W1, W2, Wd1, bd2, featsbf, WT1, WT2, WTd1, out);

    // layer 1 aggregate (d=128)
    aggregate_bf_k<FEAT><<<(NN + 3) / 4, 256, 0, stream>>>(featsbf, rowptr, col, A1);

    // fused gemm1+relu+gemm2 (pre-aggregation; agg commutes with matmul+bias)
    fused_gemm12_k<<<(NN + 63) / 64, 512, 0, stream>>>(A1, WT1, b1, WT2, b2, Y2bf, NN);

    // layer 2 aggregate (d=256)
    aggregate_bf_k<HID><<<(NN + 3) / 4, 256, 0, stream>>>(Y2bf, rowptr, col, h2bf);

    // decoder
    gemm_dec_k<HID><<<dim3((NN + 127) / 128, 2), 512, 0, stream>>>(h2bf, WTd1, bd1,
                                                                   out, Wd2, NN);
}